// Round 10
// baseline (490.482 us; speedup 1.0000x reference)
//
#include <hip/hip_runtime.h>
#include <math.h>

#define NB 16
#define LQ 512
#define LKK 2048
#define DD 1024

typedef _Float16 half8 __attribute__((ext_vector_type(8)));
typedef _Float16 half4 __attribute__((ext_vector_type(4)));
typedef float f32x4 __attribute__((ext_vector_type(4)));

__device__ __forceinline__ void gl_lds16(const void* g, void* l) {
    __builtin_amdgcn_global_load_lds(
        (const __attribute__((address_space(1))) void*)g,
        (__attribute__((address_space(3))) void*)l, 16, 0, 0);
}

// ===========================================================================
// 8-phase 256x256 NT-GEMM for QK^T  [proven R5-R9 — unchanged]
// ===========================================================================
__global__ __launch_bounds__(512, 2) void gemm_qk_256(
    const _Float16* __restrict__ A, long sA,
    const _Float16* __restrict__ B, long sB,
    _Float16* __restrict__ P, long sP,
    float* __restrict__ partial,
    float scale)
{
    __shared__ _Float16 lsA[2][256 * 64];
    __shared__ _Float16 lsB[2][256 * 64];
    const int tid = threadIdx.x;
    const int w = tid >> 6, l = tid & 63;
    const int wr = w >> 2, wc = w & 3;
    const int lrg = l >> 4, lc = l & 15, lr = lrg << 2;

    int id = blockIdx.x + gridDim.x * (blockIdx.y + gridDim.y * blockIdx.z);
    const int nwg = gridDim.x * gridDim.y * gridDim.z;
    id = (id & 7) * (nwg >> 3) + (id >> 3);
    const int bx = id % gridDim.x;
    const int t2 = id / gridDim.x;
    const int by = t2 % gridDim.y;
    const int z  = t2 / gridDim.y;
    const int m0 = by * 256, n0 = bx * 256;

    const _Float16* Ab = A + (size_t)z * sA + (size_t)m0 * DD;
    const _Float16* Bb = B + (size_t)z * sB + (size_t)n0 * DD;

    const int srow = l >> 3;
    const int sk = ((l & 7) ^ srow) << 3;

#define STG(dst, srcbase)                                                     \
    do {                                                                      \
        _Pragma("unroll")                                                     \
        for (int rr = 0; rr < 2; ++rr) {                                      \
            const int c = w + 8 * rr;                                         \
            gl_lds16((srcbase) + (size_t)(c * 8 + srow) * DD + sk,            \
                     (dst) + c * 512);                                        \
        }                                                                     \
    } while (0)

    half8 af[4][2], bf01[2][2], bf23[2][2];
    f32x4 acc[8][4] = {};
    const int rsb = (lc & 7) << 4;

#define LDA(buf, mh)                                                          \
    do {                                                                      \
        const char* p_ = (const char*)lsA[buf];                               \
        _Pragma("unroll")                                                     \
        for (int ii = 0; ii < 4; ++ii) {                                      \
            const int row_ = wr * 128 + (mh) * 64 + ii * 16 + lc;             \
            _Pragma("unroll")                                                 \
            for (int kk = 0; kk < 2; ++kk)                                    \
                af[ii][kk] = *(const half8*)(p_ + row_ * 128 +                \
                             ((kk * 64 + (lrg << 4)) ^ rsb));                 \
        }                                                                     \
    } while (0)

#define LDB(buf, nh, bfr)                                                     \
    do {                                                                      \
        const char* p_ = (const char*)lsB[buf];                               \
        _Pragma("unroll")                                                     \
        for (int jj = 0; jj < 2; ++jj) {                                      \
            const int row_ = wc * 64 + ((nh) * 2 + jj) * 16 + lc;             \
            _Pragma("unroll")                                                 \
            for (int kk = 0; kk < 2; ++kk)                                    \
                bfr[jj][kk] = *(const half8*)(p_ + row_ * 128 +               \
                              ((kk * 64 + (lrg << 4)) ^ rsb));                \
        }                                                                     \
    } while (0)

#define MM(mh, nh, bfr)                                                       \
    do {                                                                      \
        __builtin_amdgcn_s_setprio(1);                                        \
        _Pragma("unroll")                                                     \
        for (int ii = 0; ii < 4; ++ii)                                        \
            _Pragma("unroll")                                                 \
            for (int jj = 0; jj < 2; ++jj)                                    \
                _Pragma("unroll")                                             \
                for (int kk = 0; kk < 2; ++kk)                                \
                    acc[(mh) * 4 + ii][(nh) * 2 + jj] =                       \
                        __builtin_amdgcn_mfma_f32_16x16x32_f16(               \
                            af[ii][kk], bfr[jj][kk],                          \
                            acc[(mh) * 4 + ii][(nh) * 2 + jj], 0, 0, 0);      \
        __builtin_amdgcn_s_setprio(0);                                        \
    } while (0)

#define BAR __builtin_amdgcn_s_barrier()
#define VMW(n) asm volatile("s_waitcnt vmcnt(" #n ")" ::: "memory")

    STG(&lsA[0][0], Ab);
    STG(&lsA[0][128 * 64], Ab + (size_t)128 * DD);
    STG(&lsB[0][0], Bb);
    STG(&lsB[0][128 * 64], Bb + (size_t)128 * DD);
    STG(&lsA[1][0], Ab + 64);
    VMW(2);
    BAR;

    for (int i = 0; i < 7; ++i) {
        const int kt1 = (2 * i + 1) * 64, kt2 = kt1 + 64, kt3 = kt2 + 64;
        LDA(0, 0); LDB(0, 0, bf01);
        STG(&lsA[1][128 * 64], Ab + (size_t)128 * DD + kt1);
        BAR; MM(0, 0, bf01); BAR;
        LDB(0, 1, bf23);
        STG(&lsB[1][0], Bb + kt1);
        BAR; MM(0, 1, bf23); BAR;
        LDA(0, 1);
        STG(&lsB[1][128 * 64], Bb + (size_t)128 * DD + kt1);
        BAR; MM(1, 0, bf01); BAR;
        STG(&lsA[0][0], Ab + kt2);
        BAR; MM(1, 1, bf23);
        VMW(2); BAR;
        LDA(1, 0); LDB(1, 0, bf01);
        STG(&lsA[0][128 * 64], Ab + (size_t)128 * DD + kt2);
        BAR; MM(0, 0, bf01); BAR;
        LDB(1, 1, bf23);
        STG(&lsB[0][0], Bb + kt2);
        BAR; MM(0, 1, bf23); BAR;
        LDA(1, 1);
        STG(&lsB[0][128 * 64], Bb + (size_t)128 * DD + kt2);
        BAR; MM(1, 0, bf01); BAR;
        STG(&lsA[1][0], Ab + kt3);
        BAR; MM(1, 1, bf23);
        VMW(2); BAR;
    }
    {
        const int kt1 = 15 * 64;
        LDA(0, 0); LDB(0, 0, bf01);
        STG(&lsA[1][128 * 64], Ab + (size_t)128 * DD + kt1);
        BAR; MM(0, 0, bf01); BAR;
        LDB(0, 1, bf23);
        STG(&lsB[1][0], Bb + kt1);
        BAR; MM(0, 1, bf23); BAR;
        LDA(0, 1);
        STG(&lsB[1][128 * 64], Bb + (size_t)128 * DD + kt1);
        BAR; MM(1, 0, bf01); BAR;
        BAR; MM(1, 1, bf23);
        VMW(0); BAR;
        LDA(1, 0); LDB(1, 0, bf01);
        BAR; MM(0, 0, bf01); BAR;
        LDB(1, 1, bf23);
        BAR; MM(0, 1, bf23); BAR;
        LDA(1, 1);
        BAR; MM(1, 0, bf01); BAR;
        BAR; MM(1, 1, bf23);
    }
    __syncthreads();

    _Float16* Cb = P + (size_t)z * sP;
    float* psum = (float*)&lsA[0][0];
    #pragma unroll
    for (int i = 0; i < 8; ++i) {
        float rsum[4] = {0.f, 0.f, 0.f, 0.f};
        #pragma unroll
        for (int j = 0; j < 4; ++j) {
            const int n = n0 + wc * 64 + j * 16 + lc;
            #pragma unroll
            for (int r = 0; r < 4; ++r) {
                const int m = m0 + wr * 128 + i * 16 + lr + r;
                const float e = __expf(acc[i][j][r] * scale);
                Cb[(size_t)m * LKK + n] = (_Float16)e;
                rsum[r] += e;
            }
        }
        #pragma unroll
        for (int r = 0; r < 4; ++r) {
            float s = rsum[r];
            s += __shfl_xor(s, 1);
            s += __shfl_xor(s, 2);
            s += __shfl_xor(s, 4);
            s += __shfl_xor(s, 8);
            if (lc == 0) psum[(wr * 128 + i * 16 + lr + r) * 4 + wc] = s;
        }
    }
    __syncthreads();
    if (tid < 256) {
        const float* pr = psum + tid * 4;
        partial[((size_t)z * LQ + m0 + tid) * 8 + bx] = pr[0] + pr[1] + pr[2] + pr[3];
    }
#undef STG
#undef LDA
#undef LDB
#undef MM
}

// ===========================================================================
// 256x128 NT-GEMM for PV / cat — 4M x 2N waves, 3-buffer rolling schedule,
// counted vmcnt(6), 144KB LDS.  [proven R7-R9 — unchanged]
// ===========================================================================
__global__ __launch_bounds__(512, 2) void gemm_pc_256x128(
    const _Float16* __restrict__ Alo, long sAlo, int lda_lo,
    const _Float16* __restrict__ Ahi, long sAhi, int lda_hi,
    int ksplit,
    const _Float16* __restrict__ B, long sB, int ldb,
    int K, int mode,
    float* __restrict__ out32, long s32, int ldc32,
    _Float16* __restrict__ out16, long s16, int ldc16,
    const float* __restrict__ bias,
    const float* __restrict__ partial, int npart)
{
    __shared__ _Float16 ls[3][384 * 64];
    const int tid = threadIdx.x;
    const int w = tid >> 6, l = tid & 63;
    const int wr = w >> 1, wc = w & 1;     // 4M x 2N
    const int lrg = l >> 4, lc = l & 15, lr = lrg << 2;

    int id = blockIdx.x + gridDim.x * (blockIdx.y + gridDim.y * blockIdx.z);
    const int nwg = gridDim.x * gridDim.y * gridDim.z;
    id = (id & 7) * (nwg >> 3) + (id >> 3);
    const int bx = id % gridDim.x;
    const int t2_ = id / gridDim.x;
    const int by = t2_ % gridDim.y;
    const int z  = t2_ / gridDim.y;
    const int m0 = by * 256, n0 = bx * 128;

    const _Float16* Abase_lo = Alo + (size_t)z * sAlo + (size_t)m0 * lda_lo;
    const _Float16* Abase_hi = Ahi ? (Ahi + (size_t)z * sAhi + (size_t)m0 * lda_hi) : (const _Float16*)0;
    const _Float16* Bbase = B + (size_t)z * sB + (size_t)n0 * ldb;

    const int srow = l >> 3;
    const int sk = ((l & 7) ^ srow) << 3;
    const int rsb = (lc & 7) << 4;

    half8 af[4][2], bf[2][2];
    f32x4 acc[4][4] = {};

#define STGA(tt, dbuf)                                                        \
    do {                                                                      \
        const int kb_ = (tt) * 64;                                            \
        const _Float16* s_; int ld_;                                          \
        if (kb_ < ksplit) { s_ = Abase_lo + kb_;           ld_ = lda_lo; }    \
        else              { s_ = Abase_hi + (kb_ - ksplit); ld_ = lda_hi; }   \
        _Float16* d_ = &ls[dbuf][0];                                          \
        _Pragma("unroll")                                                     \
        for (int rr = 0; rr < 4; ++rr) {                                      \
            const int c = w + 8 * rr;                                         \
            gl_lds16(s_ + (size_t)(c * 8 + srow) * ld_ + sk, d_ + c * 512);   \
        }                                                                     \
    } while (0)

#define STGB(tt, dbuf)                                                        \
    do {                                                                      \
        const _Float16* s_ = Bbase + (tt) * 64;                               \
        _Float16* d_ = &ls[dbuf][256 * 64];                                   \
        _Pragma("unroll")                                                     \
        for (int rr = 0; rr < 2; ++rr) {                                      \
            const int c = w + 8 * rr;                                         \
            gl_lds16(s_ + (size_t)(c * 8 + srow) * ldb + sk, d_ + c * 512);   \
        }                                                                     \
    } while (0)

#define LDA2(buf)                                                             \
    do {                                                                      \
        const char* p_ = (const char*)&ls[buf][0];                            \
        _Pragma("unroll")                                                     \
        for (int ii = 0; ii < 4; ++ii) {                                      \
            const int row_ = wr * 64 + ii * 16 + lc;                          \
            _Pragma("unroll")                                                 \
            for (int kk = 0; kk < 2; ++kk)                                    \
                af[ii][kk] = *(const half8*)(p_ + row_ * 128 +                \
                             ((kk * 64 + (lrg << 4)) ^ rsb));                 \
        }                                                                     \
    } while (0)

#define LDB2(buf, nh)                                                         \
    do {                                                                      \
        const char* p_ = (const char*)&ls[buf][256 * 64];                     \
        _Pragma("unroll")                                                     \
        for (int jj = 0; jj < 2; ++jj) {                                      \
            const int row_ = wc * 64 + ((nh) * 2 + jj) * 16 + lc;             \
            _Pragma("unroll")                                                 \
            for (int kk = 0; kk < 2; ++kk)                                    \
                bf[jj][kk] = *(const half8*)(p_ + row_ * 128 +                \
                              ((kk * 64 + (lrg << 4)) ^ rsb));                \
        }                                                                     \
    } while (0)

#define MM2(nh)                                                               \
    do {                                                                      \
        __builtin_amdgcn_s_setprio(1);                                        \
        _Pragma("unroll")                                                     \
        for (int ii = 0; ii < 4; ++ii)                                        \
            _Pragma("unroll")                                                 \
            for (int jj = 0; jj < 2; ++jj)                                    \
                _Pragma("unroll")                                             \
                for (int kk = 0; kk < 2; ++kk)                                \
                    acc[ii][(nh) * 2 + jj] =                                  \
                        __builtin_amdgcn_mfma_f32_16x16x32_f16(               \
                            af[ii][kk], bf[jj][kk],                           \
                            acc[ii][(nh) * 2 + jj], 0, 0, 0);                 \
        __builtin_amdgcn_s_setprio(0);                                        \
    } while (0)

    const int NT = K >> 6;
    STGA(0, 0); STGB(0, 0);
    STGA(1, 1); STGB(1, 1);
    VMW(6);
    BAR;

    int b = 0, b2 = 2;
    for (int t = 0; t < NT; ++t) {
        const int tt = t + 2;
        const bool st = tt < NT;
        LDA2(b); LDB2(b, 0);
        if (st) STGA(tt, b2);
        BAR; MM2(0); BAR;
        LDB2(b, 1);
        if (st) STGB(tt, b2);
        BAR; MM2(1);
        if (t < NT - 2)       VMW(6);
        else if (t == NT - 2) VMW(0);
        BAR;
        b = (b == 2) ? 0 : b + 1;
        b2 = (b2 == 2) ? 0 : b2 + 1;
    }
    __syncthreads();

    if (mode == 1) {
        float* psum = (float*)&ls[0][0];
        if (tid < 256) {
            const float* pp = partial + ((size_t)z * LQ + m0 + tid) * npart;
            float s = 0.0f;
            for (int c = 0; c < npart; ++c) s += pp[c];
            psum[tid] = 1.0f / s;
        }
        __syncthreads();
        _Float16* Cb = out16 + (size_t)z * s16;
        #pragma unroll
        for (int i = 0; i < 4; ++i)
            #pragma unroll
            for (int j = 0; j < 4; ++j) {
                const int n = n0 + wc * 64 + j * 16 + lc;
                #pragma unroll
                for (int r = 0; r < 4; ++r) {
                    const int ml = wr * 64 + i * 16 + lr + r;
                    Cb[(size_t)(m0 + ml) * ldc16 + n] =
                        (_Float16)(acc[i][j][r] * psum[ml]);
                }
            }
    } else {
        float bv[4];
        #pragma unroll
        for (int j = 0; j < 4; ++j)
            bv[j] = bias[n0 + wc * 64 + j * 16 + lc];
        #pragma unroll
        for (int i = 0; i < 4; ++i)
            #pragma unroll
            for (int j = 0; j < 4; ++j) {
                const int n = n0 + wc * 64 + j * 16 + lc;
                #pragma unroll
                for (int r = 0; r < 4; ++r) {
                    const int m = m0 + wr * 64 + i * 16 + lr + r;
                    const float t = tanhf(acc[i][j][r] + bv[j]);
                    if (out16) out16[(size_t)z * s16 + (size_t)m * ldc16 + n] = (_Float16)t;
                    if (out32) out32[(size_t)z * s32 + (size_t)m * ldc32 + n] = t;
                }
            }
    }
#undef STGA
#undef STGB
#undef LDA2
#undef LDB2
#undef MM2
#undef BAR
#undef VMW
}

// ---------------------------------------------------------------------------
// f16 MFMA NT-GEMM 128x128 (R3-fallback path only)
// ---------------------------------------------------------------------------
__global__ __launch_bounds__(256) void gemm_f16_nt(
    const _Float16* __restrict__ Alo, long sAlo, int lda_lo,
    const _Float16* __restrict__ Ahi, long sAhi, int lda_hi,
    int ksplit,
    const _Float16* __restrict__ B, long sB, int ldb,
    int K, int mode, float scale,
    float* __restrict__ out32, long s32, int ldc32,
    _Float16* __restrict__ out16, long s16, int ldc16,
    const float* __restrict__ bias,
    float* __restrict__ partial, const float* __restrict__ inv, int npart)
{
    __shared__ _Float16 lsA[128 * 64];
    __shared__ _Float16 lsB[128 * 64];
    __shared__ float psum[128][2];
    const int tid = threadIdx.x;
    const int w = tid >> 6, l = tid & 63;
    const int wr = w >> 1, wc = w & 1;

    int id = blockIdx.x + gridDim.x * (blockIdx.y + gridDim.y * blockIdx.z);
    const int nwg = gridDim.x * gridDim.y * gridDim.z;
    id = (id & 7) * (nwg >> 3) + (id >> 3);
    const int bx = id % gridDim.x;
    const int t2 = id / gridDim.x;
    const int by = t2 % gridDim.y;
    const int z = t2 / gridDim.y;
    const int m0 = by * 128, n0 = bx * 128;

    const _Float16* Abase_lo = Alo + (size_t)z * sAlo + (size_t)m0 * lda_lo;
    const _Float16* Abase_hi = Ahi ? (Ahi + (size_t)z * sAhi + (size_t)m0 * lda_hi) : (const _Float16*)0;
    const _Float16* Bbase = B + (size_t)z * sB + (size_t)n0 * ldb;

    const int srow = l >> 3;
    const int sswz = ((l & 7) ^ srow) << 3;

    f32x4 acc[4][4] = {};

    for (int k0 = 0; k0 < K; k0 += 64) {
        const _Float16* Ap; int kloc, ldaA;
        if (k0 < ksplit) { Ap = Abase_lo; kloc = k0;          ldaA = lda_lo; }
        else             { Ap = Abase_hi; kloc = k0 - ksplit; ldaA = lda_hi; }
        #pragma unroll
        for (int i = 0; i < 4; ++i) {
            const int c = w * 4 + i;
            const int row = c * 8 + srow;
            gl_lds16(Ap + (size_t)row * ldaA + kloc + sswz, &lsA[c * 512]);
        }
        #pragma unroll
        for (int i = 0; i < 4; ++i) {
            const int c = w * 4 + i;
            const int row = c * 8 + srow;
            gl_lds16(Bbase + (size_t)row * ldb + k0 + sswz, &lsB[c * 512]);
        }
        __syncthreads();

        half8 af[4][2], bf[4][2];
        const char* lA = (const char*)lsA;
        const char* lB = (const char*)lsB;
        const int rs = (l & 7) << 4;
        const int cb = (l >> 4) << 4;
        #pragma unroll
        for (int i = 0; i < 4; ++i) {
            const int rowa = wr * 64 + i * 16 + (l & 15);
            const int rowb = wc * 64 + i * 16 + (l & 15);
            #pragma unroll
            for (int kk = 0; kk < 2; ++kk) {
                af[i][kk] = *(const half8*)(lA + rowa * 128 + ((kk * 64 + cb) ^ rs));
                bf[i][kk] = *(const half8*)(lB + rowb * 128 + ((kk * 64 + cb) ^ rs));
            }
        }
        #pragma unroll
        for (int kk = 0; kk < 2; ++kk)
            #pragma unroll
            for (int i = 0; i < 4; ++i)
                #pragma unroll
                for (int j = 0; j < 4; ++j)
                    acc[i][j] = __builtin_amdgcn_mfma_f32_16x16x32_f16(
                        af[i][kk], bf[j][kk], acc[i][j], 0, 0, 0);
        __syncthreads();
    }

    const int lr = (l >> 4) * 4;
    const int lc = l & 15;
    if (mode == 0) {
        _Float16* Cb = out16 + (size_t)z * s16;
        float rsum[4][4];
        #pragma unroll
        for (int i = 0; i < 4; ++i)
            #pragma unroll
            for (int r = 0; r < 4; ++r) rsum[i][r] = 0.0f;
        #pragma unroll
        for (int i = 0; i < 4; ++i)
            #pragma unroll
            for (int j = 0; j < 4; ++j) {
                const int n = n0 + wc * 64 + j * 16 + lc;
                #pragma unroll
                for (int r = 0; r < 4; ++r) {
                    const int m = m0 + wr * 64 + i * 16 + lr + r;
                    const float e = __expf(acc[i][j][r] * scale);
                    Cb[(size_t)m * ldc16 + n] = (_Float16)e;
                    rsum[i][r] += e;
                }
            }
        #pragma unroll
        for (int i = 0; i < 4; ++i)
            #pragma unroll
            for (int r = 0; r < 4; ++r) {
                float s = rsum[i][r];
                s += __shfl_xor(s, 1);
                s += __shfl_xor(s, 2);
                s += __shfl_xor(s, 4);
                s += __shfl_xor(s, 8);
                rsum[i][r] = s;
            }
        if (lc == 0) {
            #pragma unroll
            for (int i = 0; i < 4; ++i)
                #pragma unroll
                for (int r = 0; r < 4; ++r)
                    psum[wr * 64 + i * 16 + lr + r][wc] = rsum[i][r];
        }
        __syncthreads();
        if (tid < 128)
            partial[((size_t)z * LQ + m0 + tid) * npart + bx] = psum[tid][0] + psum[tid][1];
    } else if (mode == 1) {
        _Float16* Cb = out16 + (size_t)z * s16;
        float iv[4][4];
        if (partial) {
            if (tid < 128) {
                const float* pp = partial + ((size_t)z * LQ + m0 + tid) * npart;
                float s = 0.0f;
                for (int c = 0; c < npart; ++c) s += pp[c];
                psum[tid][0] = 1.0f / s;
            }
            __syncthreads();
            #pragma unroll
            for (int i = 0; i < 4; ++i)
                #pragma unroll
                for (int r = 0; r < 4; ++r)
                    iv[i][r] = psum[wr * 64 + i * 16 + lr + r][0];
        } else {
            #pragma unroll
            for (int i = 0; i < 4; ++i)
                #pragma unroll
                for (int r = 0; r < 4; ++r)
                    iv[i][r] = inv ? inv[(size_t)z * LQ + m0 + wr * 64 + i * 16 + lr + r] : 1.0f;
        }
        #pragma unroll
        for (int i = 0; i < 4; ++i)
            #pragma unroll
            for (int j = 0; j < 4; ++j) {
                const int n = n0 + wc * 64 + j * 16 + lc;
                #pragma unroll
                for (int r = 0; r < 4; ++r) {
                    const int m = m0 + wr * 64 + i * 16 + lr + r;
                    Cb[(size_t)m * ldc16 + n] = (_Float16)(acc[i][j][r] * iv[i][r]);
                }
            }
    } else if (mode == 4) {
        float* Cb = out32 + (size_t)z * s32;
        #pragma unroll
        for (int i = 0; i < 4; ++i)
            #pragma unroll
            for (int j = 0; j < 4; ++j) {
                const int n = n0 + wc * 64 + j * 16 + lc;
                #pragma unroll
                for (int r = 0; r < 4; ++r) {
                    const int m = m0 + wr * 64 + i * 16 + lr + r;
                    Cb[(size_t)m * ldc32 + n] = acc[i][j][r] * scale;
                }
            }
    } else {
        float bv[4];
        #pragma unroll
        for (int j = 0; j < 4; ++j)
            bv[j] = bias[n0 + wc * 64 + j * 16 + lc];
        #pragma unroll
        for (int i = 0; i < 4; ++i)
            #pragma unroll
            for (int j = 0; j < 4; ++j) {
                const int n = n0 + wc * 64 + j * 16 + lc;
                #pragma unroll
                for (int r = 0; r < 4; ++r) {
                    const int m = m0 + wr * 64 + i * 16 + lr + r;
                    const float t = tanhf(acc[i][j][r] + bv[j]);
                    if (out16) out16[(size_t)z * s16 + (size_t)m * ldc16 + n] = (_Float16)t;
                    if (out32) out32[(size_t)z * s32 + (size_t)m * ldc32 + n] = t;
                }
            }
    }
}

// one block per row: attn_f32[row,:] = P16[row,:] * (1/sum partial[row,0..npart))
__global__ __launch_bounds__(256) void scale_attn(
    const _Float16* __restrict__ P, const float* __restrict__ partial,
    float* __restrict__ attn, int npart)
{
    __shared__ float sinv;
    const long row = blockIdx.x;
    const int tid = threadIdx.x;
    if (tid < npart) {
        float s = partial[row * npart + tid];
        for (int off = npart >> 1; off > 0; off >>= 1) s += __shfl_xor(s, off);
        if (tid == 0) sinv = 1.0f / s;
    }
    __syncthreads();
    const float inv = sinv;
    const half8 h = *(const half8*)(P + row * 2048 + tid * 8);
    float* o = attn + row * 2048 + tid * 8;
    float4 a = make_float4((float)h[0] * inv, (float)h[1] * inv,
                           (float)h[2] * inv, (float)h[3] * inv);
    float4 b = make_float4((float)h[4] * inv, (float)h[5] * inv,
                           (float)h[6] * inv, (float)h[7] * inv);
    *(float4*)o = a;
    *(float4*)(o + 4) = b;
}

// inv[row] = 1 / sum_{cb<16} partial[row*16+cb]   (R3-fallback path)
__global__ __launch_bounds__(256) void make_inv(
    const float* __restrict__ partial, float* __restrict__ inv)
{
    const int row = blockIdx.x * 256 + threadIdx.x;
    const float4 a = *(const float4*)(partial + (size_t)row * 16);
    const float4 b = *(const float4*)(partial + (size_t)row * 16 + 4);
    const float4 c = *(const float4*)(partial + (size_t)row * 16 + 8);
    const float4 d = *(const float4*)(partial + (size_t)row * 16 + 12);
    const float s = (a.x + a.y + a.z + a.w) + (b.x + b.y + b.z + b.w)
                  + (c.x + c.y + c.z + c.w) + (d.x + d.y + d.z + d.w);
    inv[row] = 1.0f / s;
}

// row softmax over 2048 f32 (R3-fallback hop 2)
__global__ __launch_bounds__(256) void softmax_rows2(
    float* __restrict__ S, _Float16* __restrict__ f16out,
    long f16stride, int write_f32)
{
    __shared__ float red[8];
    const long row = blockIdx.x;
    float* p = S + row * LKK;
    const int tid = threadIdx.x;
    float4 v0 = ((const float4*)p)[tid];
    float4 v1 = ((const float4*)p)[tid + 256];
    float m = fmaxf(fmaxf(fmaxf(v0.x, v0.y), fmaxf(v0.z, v0.w)),
                    fmaxf(fmaxf(v1.x, v1.y), fmaxf(v1.z, v1.w)));
    #pragma unroll
    for (int off = 32; off > 0; off >>= 1) m = fmaxf(m, __shfl_down(m, off));
    if ((tid & 63) == 0) red[tid >> 6] = m;
    __syncthreads();
    m = fmaxf(fmaxf(red[0], red[1]), fmaxf(red[2], red[3]));
    v0.x = expf(v0.x - m); v0.y = expf(v0.y - m);
    v0.z = expf(v0.z - m); v0.w = expf(v0.w - m);
    v1.x = expf(v1.x - m); v1.y = expf(v1.y - m);
    v1.z = expf(v1.z - m); v1.w = expf(v1.w - m);
    float s = v0.x + v0.y + v0.z + v0.w + v1.x + v1.y + v1.z + v1.w;
    #pragma unroll
    for (int off = 32; off > 0; off >>= 1) s += __shfl_down(s, off);
    if ((tid & 63) == 0) red[4 + (tid >> 6)] = s;
    __syncthreads();
    s = red[4] + red[5] + red[6] + red[7];
    const float inv = 1.0f / s;
    v0.x *= inv; v0.y *= inv; v0.z *= inv; v0.w *= inv;
    v1.x *= inv; v1.y *= inv; v1.z *= inv; v1.w *= inv;
    if (write_f32) {
        ((float4*)p)[tid] = v0;
        ((float4*)p)[tid + 256] = v1;
    }
    _Float16* q = f16out + row * f16stride;
    half4 h0 = { (_Float16)v0.x, (_Float16)v0.y, (_Float16)v0.z, (_Float16)v0.w };
    half4 h1 = { (_Float16)v1.x, (_Float16)v1.y, (_Float16)v1.z, (_Float16)v1.w };
    *(half4*)(q + tid * 4) = h0;
    *(half4*)(q + 1024 + tid * 4) = h1;
}

__global__ __launch_bounds__(256) void cvt_f32_to_f16(
    const float* __restrict__ in, _Float16* __restrict__ out, long n)
{
    const long i = ((long)blockIdx.x * 256 + threadIdx.x) * 8;
    if (i + 8 > n) return;
    float4 a = *(const float4*)(in + i);
    float4 b = *(const float4*)(in + i + 4);
    half8 h = { (_Float16)a.x, (_Float16)a.y, (_Float16)a.z, (_Float16)a.w,
                (_Float16)b.x, (_Float16)b.y, (_Float16)b.z, (_Float16)b.w };
    *(half8*)(out + i) = h;
}

// V [B, Lk, D] f32 -> Vt [B, D, Lk] f16, 64x64 tiles via LDS (fallback paths)
__global__ __launch_bounds__(256) void transpose_cvt_v(
    const float* __restrict__ V, _Float16* __restrict__ Vt)
{
    __shared__ _Float16 t[64][80];
    const int z = blockIdx.z;
    const int k0 = blockIdx.y * 64, d0 = blockIdx.x * 64;
    const float* Vb = V + (size_t)z * LKK * DD;
    _Float16* Vtb = Vt + (size_t)z * DD * LKK;
    const int r = threadIdx.x >> 2;
    const int c0 = (threadIdx.x & 3) * 16;
    #pragma unroll
    for (int j = 0; j < 4; ++j) {
        float4 v = *(const float4*)(Vb + (size_t)(k0 + r) * DD + d0 + c0 + j * 4);
        t[c0 + j * 4 + 0][r] = (_Float16)v.x;
        t[c0 + j * 4 + 1][r] = (_Float16)v.y;
        t[c0 + j * 4 + 2][r] = (_Float16)v.z;
        t[c0 + j * 4 + 3][r] = (_Float16)v.w;
    }
    __syncthreads();
    #pragma unroll
    for (int j = 0; j < 2; ++j) {
        half8 h = *(const half8*)&t[r][c0 + j * 8];
        *(half8*)(Vtb + (size_t)(d0 + r) * LKK + k0 + c0 + j * 8) = h;
    }
}

// ===========================================================================
// R10 prep: fat blocks, one dispatch.
//   cvt blocks [0,5376): 4 chunks/thread (8 indep float4 loads in flight)
//     Q: [0,1024)  K: [1024,5120)  W: [5120,5376)  — each block = 8192 halves
//   V-transpose blocks [5376,9472): 2 k-tiles per block, pad 82 (2-way free)
// ===========================================================================
__global__ __launch_bounds__(256) void prep_all(
    const float* __restrict__ Q, const float* __restrict__ K,
    const float* __restrict__ W, const float* __restrict__ V,
    _Float16* __restrict__ Qh, _Float16* __restrict__ Kh,
    _Float16* __restrict__ Wh, _Float16* __restrict__ Vt)
{
    __shared__ _Float16 t[64][82];
    const int b = blockIdx.x;
    const int tid = threadIdx.x;

    if (b < 5376) {
        const float* src; _Float16* dst; long bloc;
        if (b < 1024)      { src = Q; dst = Qh; bloc = b; }
        else if (b < 5120) { src = K; dst = Kh; bloc = b - 1024; }
        else               { src = W; dst = Wh; bloc = b - 5120; }
        #pragma unroll
        for (int c = 0; c < 4; ++c) {
            const long i = (bloc * 1024 + c * 256 + tid) * 8L;
            float4 a  = *(const float4*)(src + i);
            float4 cc = *(const float4*)(src + i + 4);
            half8 h = { (_Float16)a.x,  (_Float16)a.y,  (_Float16)a.z,  (_Float16)a.w,
                        (_Float16)cc.x, (_Float16)cc.y, (_Float16)cc.z, (_Float16)cc.w };
            *(half8*)(dst + i) = h;
        }
        return;
    }
    // V transpose: bb in [0,4096): dx 16 x ky2 16 x z 16; 2 k-tiles per block
    const int bb = b - 5376;
    const int dx  = bb & 15;
    const int ky2 = (bb >> 4) & 15;
    const int z   = bb >> 8;
    const int d0 = dx * 64;
    const float* Vb = V + (size_t)z * LKK * DD;
    _Float16* Vtb = Vt + (size_t)z * DD * LKK;
    const int r = tid >> 2;
    const int c0 = (tid & 3) * 16;
    for (int half = 0; half < 2; ++half) {
        const int k0 = (ky2 * 2 + half) * 64;
        #pragma unroll
        for (int j = 0; j < 4; ++j) {
            float4 v = *(const float4*)(Vb + (size_t)(k0 + r) * DD + d0 + c0 + j * 4);
            t[c0 + j * 4 + 0][r] = (_Float16)v.x;
            t[c0 + j * 4 + 1][r] = (_Float16)v.y;
            t[c0 + j * 4 + 2][r] = (_Float16)v.z;
            t[c0 + j * 4 + 3][r] = (_Float16)v.w;
        }
        __syncthreads();
        #pragma unroll
        for (int j = 0; j < 2; ++j) {
            half8 h = *(const half8*)&t[r][c0 + j * 8];
            *(half8*)(Vtb + (size_t)(d0 + r) * LKK + k0 + c0 + j * 8) = h;
        }
        __syncthreads();
    }
}

// ======================= round-1 f32 fallback kernels =======================
constexpr int TM = 64, TN = 64, TK = 32;
constexpr int PAD = 4;

__global__ __launch_bounds__(256) void gemm_nt_k(
    const float* __restrict__ A, int lda, long sA,
    const float* __restrict__ Bt, int ldb, long sB,
    float* __restrict__ C, int ldc, long sC, int K, float scale)
{
    __shared__ float As[TK][TM + PAD];
    __shared__ float Bs[TK][TN + PAD];
    const float* Ab = A + (long)blockIdx.z * sA;
    const float* Bb = Bt + (long)blockIdx.z * sB;
    float* Cb = C + (long)blockIdx.z * sC;
    const int m0 = blockIdx.y * TM, n0 = blockIdx.x * TN;
    const int tid = threadIdx.x;
    const int tn = tid & 15, tm = tid >> 4;
    float acc[4][4] = {};
    for (int k0 = 0; k0 < K; k0 += TK) {
        #pragma unroll
        for (int c = tid; c < (TM * TK) / 4; c += 256) {
            const int row = c >> 3, kc = (c & 7) << 2;
            const float4 g = *(const float4*)(Ab + (long)(m0 + row) * lda + (k0 + kc));
            As[kc + 0][row] = g.x; As[kc + 1][row] = g.y;
            As[kc + 2][row] = g.z; As[kc + 3][row] = g.w;
        }
        #pragma unroll
        for (int c = tid; c < (TN * TK) / 4; c += 256) {
            const int row = c >> 3, kc = (c & 7) << 2;
            const float4 g = *(const float4*)(Bb + (long)(n0 + row) * ldb + (k0 + kc));
            Bs[kc + 0][row] = g.x; Bs[kc + 1][row] = g.y;
            Bs[kc + 2][row] = g.z; Bs[kc + 3][row] = g.w;
        }
        __syncthreads();
        #pragma unroll
        for (int kk = 0; kk < TK; ++kk) {
            const float4 av = *(const float4*)&As[kk][tm << 2];
            const float4 bv = *(const float4*)&Bs[kk][tn << 2];
            const float a[4] = {av.x, av.y, av.z, av.w};
            const float b[4] = {bv.x, bv.y, bv.z, bv.w};
            #pragma unroll
            for (int i = 0; i < 4; ++i)
                #pragma unroll
                for (int j = 0; j < 4; ++j)
                    acc[i][j] = fmaf(a[i], b[j], acc[i][j]);
        }
        __syncthreads();
    }
    #pragma unroll
    for (int i = 0; i < 4; ++i) {
        float4 o = make_float4(acc[i][0] * scale, acc[i][1] * scale,
                               acc[i][2] * scale, acc[i][3] * scale);
        *(float4*)(Cb + (long)(m0 + (tm << 2) + i) * ldc + n0 + (tn << 2)) = o;
    }
}

__global__ __launch_bounds__(256) void gemm_nn_k(
    const float* __restrict__ A, int lda, long sA,
    const float* __restrict__ B, int ldb, long sB,
    float* __restrict__ C, int ldc, long sC, int K)
{
    __shared__ float As[TK][TM + PAD];
    __shared__ float Bs[TK][TN + PAD];
    const float* Ab = A + (long)blockIdx.z * sA;
    const float* Bb = B + (long)blockIdx.z * sB;
    float* Cb = C + (long)blockIdx.z * sC;
    const int m0 = blockIdx.y * TM, n0 = blockIdx.x * TN;
    const int tid = threadIdx.x;
    const int tn = tid & 15, tm = tid >> 4;
    float acc[4][4] = {};
    for (int k0 = 0; k0 < K; k0 += TK) {
        #pragma unroll
        for (int c = tid; c < (TM * TK) / 4; c += 256) {
            const int row = c >> 3, kc = (c & 7) << 2;
            const float4 g = *(const float4*)(Ab + (long)(m0 + row) * lda + (k0 + kc));
            As[kc + 0][row] = g.x; As[kc + 1][row] = g.y;
            As[kc + 2][row] = g.z; As[kc + 3][row] = g.w;
        }
        #pragma unroll
        for (int c = tid; c < (TK * TN) / 4; c += 256) {
            const int krow = c >> 4, nc = (c & 15) << 2;
            *(float4*)&Bs[krow][nc] =
                *(const float4*)(Bb + (long)(k0 + krow) * ldb + n0 + nc);
        }
        __syncthreads();
        #pragma unroll
        for (int kk = 0; kk < TK; ++kk) {
            const float4 av = *(const float4*)&As[kk][tm << 2];
            const float4 bv = *(const float4*)&Bs[kk][tn << 2];
            const float a[4] = {av.x, av.y, av.z, av.w};
            const float b[4] = {bv.x, bv.y, bv.z, bv.w};
            #pragma unroll
            for (int i = 0; i < 4; ++i)
                #pragma unroll
                for (int j = 0; j < 4; ++j)
                    acc[i][j] = fmaf(a[i], b[j], acc[i][j]);
        }
        __syncthreads();
    }
    #pragma unroll
    for (int i = 0; i < 4; ++i) {
        float4 o = make_float4(acc[i][0], acc[i][1], acc[i][2], acc[i][3]);
        *(float4*)(Cb + (long)(m0 + (tm << 2) + i) * ldc + n0 + (tn << 2)) = o;
    }
}

__global__ __launch_bounds__(256) void gemm_cat_k(
    const float* __restrict__ Qh, const float* __restrict__ R,
    const float* __restrict__ W, const float* __restrict__ bias,
    float* __restrict__ C)
{
    __shared__ float As[TK][TM + PAD];
    __shared__ float Bs[TK][TN + PAD];
    const float* Qb = Qh + (long)blockIdx.z * LQ * DD;
    const float* Rb = R + (long)blockIdx.z * LQ * DD;
    float* Cb = C + (long)blockIdx.z * LQ * DD;
    const int m0 = blockIdx.y * TM, n0 = blockIdx.x * TN;
    const int tid = threadIdx.x;
    const int tn = tid & 15, tm = tid >> 4;
    float acc[4][4] = {};
    for (int k0 = 0; k0 < 2 * DD; k0 += TK) {
        const float* src = (k0 < DD) ? Qb : Rb;
        const int kb = (k0 < DD) ? k0 : k0 - DD;
        #pragma unroll
        for (int c = tid; c < (TM * TK) / 4; c += 256) {
            const int row = c >> 3, kc = (c & 7) << 2;
            const float4 g = *(const float4*)(src + (long)(m0 + row) * DD + (kb + kc));
            As[kc + 0][row] = g.x; As[kc + 1][row] = g.y;
            As[kc + 2][row] = g.z; As[kc + 3][row] = g.w;
        }
        #pragma unroll
        for (int c = tid; c < (TN * TK) / 4; c += 256) {
            const int row = c >> 3, kc = (c & 7) << 2;
            const float4 g = *(const float4*)(W + (long)(n0 + row) * (2 * DD) + (k0 + kc));
            Bs[kc + 0][row] = g.x; Bs[kc + 1][row] = g.y;
            Bs[kc + 2][row] = g.z; Bs[kc + 3][row] = g.w;
        }
        __syncthreads();
        #pragma unroll
        for (int kk = 0; kk < TK; ++kk) {
            const float4 av = *(const float4*)&As[kk][tm << 2];
            const float4 bv = *(const float4*)&Bs[kk][tn << 2];
            const float a[4] = {av.x, av.y, av.z, av.w};
            const float b[4] = {bv.x, bv.y, bv.z, bv.w};
            #pragma unroll
            for (int i = 0; i < 4; ++i)
                #pragma unroll
                for (int j = 0; j < 4; ++j)
                    acc[i][j] = fmaf(a[i], b[j], acc[i][j]);
        }
        __syncthreads();
    }
    #pragma unroll
    for (int i = 0; i < 4; ++i) {
        float4 o;
        o.x = tanhf(acc[i][0] + bias[n0 + (tn << 2) + 0]);
        o.y = tanhf(acc[i][1] + bias[n0 + (tn << 2) + 1]);
        o.z = tanhf(acc[i][2] + bias[n0 + (tn << 2) + 2]);
        o.w = tanhf(acc[i][3] + bias[n0 + (tn << 2) + 3]);
        *(float4*)(Cb + (long)(m0 + (tm << 2) + i) * DD + n0 + (tn << 2)) = o;
    }
}

__global__ __launch_bounds__(256) void softmax_rows(float* __restrict__ S) {
    __shared__ float red[8];
    float* p = S + (size_t)blockIdx.x * LKK;
    const int tid = threadIdx.x;
    float4 v0 = ((const float4*)p)[tid];
    float4 v1 = ((const float4*)p)[tid + 256];
    float m = fmaxf(fmaxf(fmaxf(v0.x, v0.y), fmaxf(v0.z, v0.w)),
                    fmaxf(fmaxf(v1.x, v1.y), fmaxf(v1.z, v1.w)));
    #pragma unroll
    for (int off = 32; off > 0; off >>= 1) m = fmaxf(m, __shfl_down(m, off));
    if ((tid & 63) == 0) red[tid >> 6] = m;
    __syncthreads();
    m = fmaxf(fmaxf(red[0], red[1]), fmaxf(red[2], red[3]));
    v0.x = expf(v0.x - m); v0.y = expf(v0.y - m);
    v0.z = expf(v0.z - m); v0.w = expf(v0.w - m);
    v1.x = expf(v1.x - m); v1.y = expf(v1.y - m);
    v1.z = expf(v1.z - m); v1.w = expf(v1.w - m);
    float s = v0.x + v0.y + v0.z + v0.w + v1.x + v1.y + v1.z + v1.w;
    #pragma unroll
    for (int off = 32; off > 0; off >>= 1) s += __shfl_down(s, off);
    if ((tid & 63) == 0) red[4 + (tid >> 6)] = s;
    __syncthreads();
    s = red[4] + red[5] + red[6] + red[7];
    const float inv = 1.0f / s;
    v0.x *= inv; v0.y *= inv; v0.z *= inv; v0.w *= inv;
    v1.x *= inv; v1.y *= inv; v1.z *= inv; v1.w *= inv;
    ((float4*)p)[tid] = v0;
    ((float4*)p)[tid + 256] = v1;
}

// ===========================================================================
extern "C" void kernel_launch(void* const* d_in, const int* in_sizes, int n_in,
                              void* d_out, int out_size, void* d_ws, size_t ws_size,
                              hipStream_t stream) {
    const float* Q    = (const float*)d_in[0];
    const float* Km   = (const float*)d_in[1];
    const float* V    = (const float*)d_in[2];
    const float* W    = (const float*)d_in[3];
    const float* bias = (const float*)d_in[4];
    const float scale = 0.03125f;  // 1/sqrt(1024)
    dim3 blk(256);

    const size_t NEED_FULL = 189267968ULL;
    const size_t NEED_R3   = 155189248ULL;

    if (ws_size >= NEED_FULL) {
        char* ws = (char*)d_ws;
        _Float16* Kh     = (_Float16*)ws;                    // [16,2048,1024]
        _Float16* Vt     = (_Float16*)(ws + 67108864);       // [16,1024,2048]
        _Float16* Wh     = (_Float16*)(ws + 134217728);      // [1024,2048]
        _Float16* Rh     = (_Float16*)(ws + 138412032);      // [16,512,1024]
        _Float16* Qping  = (_Float16*)(ws + 155189248);      // [16,512,1024]
        _Float16* Qpong  = (_Float16*)(ws + 171966464);      // [16,512,1024]
        float*    partialB = (float*)(ws + 188743680);       // [8192,8]

        float*    outQ  = (float*)d_out;
        _Float16* P2    = (_Float16*)d_out;
        float*    attnF = (float*)((char*)d_out + 33554432);
        _Float16* P01   = (_Float16*)attnF;

        // R10: fat-block single prep dispatch
        prep_all<<<9472, blk, 0, stream>>>(Q, Km, W, V, Qping, Kh, Wh, Vt);

        dim3 gS2(LKK / 256, LQ / 256, NB);  // 8 x 2 x 16 = 256 blocks
        dim3 gP(DD / 128, LQ / 256, NB);    // 8 x 2 x 16 = 256 blocks

        for (int h = 0; h < 3; ++h) {
            _Float16* qcur = (h == 1) ? Qpong : Qping;
            _Float16* P    = (h == 2) ? P2 : P01;

            gemm_qk_256<<<gS2, dim3(512), 0, stream>>>(
                qcur, (long)LQ * DD, Kh, (long)LKK * DD,
                P, (long)LQ * LKK, partialB, scale);
            if (h == 2)
                scale_attn<<<NB * LQ, blk, 0, stream>>>(P2, partialB, attnF, 8);
            gemm_pc_256x128<<<gP, dim3(512), 0, stream>>>(
                P, (long)LQ * LKK, LKK,
                (const _Float16*)0, 0, 0, LKK * 16,   // ksplit > K: lo only
                Vt, (long)DD * LKK, LKK,
                LKK, 1,
                (float*)0, 0, 0,
                Rh, (long)LQ * DD, DD,
                (const float*)0, partialB, 8);
            _Float16* qn = (h == 0) ? Qpong : (h == 1) ? Qping : (_Float16*)0;
            float* fo = (h == 2) ? outQ : (float*)0;
            gemm_pc_256x128<<<gP, dim3(512), 0, stream>>>(
                qcur, (long)LQ * DD, DD,
                Rh, (long)LQ * DD, DD, DD,            // ksplit = 1024
                Wh, 0, 2 * DD,
                2 * DD, 2,
                fo, (long)LQ * DD, DD,
                qn, (long)LQ * DD, DD,
                bias, (const float*)0, 0);
        }
    } else if (ws_size >= NEED_R3) {
        // -------- proven R3 path --------
        char* ws = (char*)d_ws;
        _Float16* Kh  = (_Float16*)ws;
        _Float16* Vt  = (_Float16*)(ws + 67108864);
        _Float16* Wh  = (_Float16*)(ws + 134217728);
        _Float16* Rh  = (_Float16*)(ws + 138412032);
        _Float16* attn2 = (_Float16*)ws;
        float* Fout = (float*)(ws + 33554432);

        _Float16* Qping = (_Float16*)d_out;
        _Float16* Qpong = Qping + (size_t)NB * LQ * DD;
        float* S = (float*)((char*)d_out + 33554432);
        _Float16* P = (_Float16*)S;
        float* partialB = (float*)((char*)d_out + 73400320);
        float* invB     = (float*)((char*)d_out + 73924608);

        cvt_f32_to_f16<<<4096, blk, 0, stream>>>(Q, Qping, (long)NB * LQ * DD);
        cvt_f32_to_f16<<<16384, blk, 0, stream>>>(Km, Kh, (long)NB * LKK * DD);
        cvt_f32_to_f16<<<1024, blk, 0, stream>>>(W, Wh, (long)DD * 2 * DD);
        transpose_cvt_v<<<dim3(DD / 64, LKK / 64, NB), blk, 0, stream>>>(V, Vt);

        dim3 gS(LKK / 128, LQ / 128, NB);
        dim3 gR(DD / 128, LQ / 128, NB);

        for (int h = 0; h < 3; ++h) {
            _Float16* qcur = (h == 1) ? Qpong : Qping;
            if (h < 2) {
                gemm_f16_nt<<<gS, blk, 0, stream>>>(
                    qcur, (long)LQ * DD, DD, (const _Float16*)0, 0, 0, DD,
                    Kh, (long)LKK * DD, DD, DD,
                    0, scale, (float*)0, 0, 0,
                    P, (long)LQ * LKK, LKK, (const float*)0,
                    partialB, (const float*)0, 16);
                make_inv<<<32, blk, 0, stream>>>(partialB, invB);
                gemm_f16_nt<<<gR, blk, 0, stream>>>(
                    P, (long)LQ * LKK, LKK,
                    (const _Float16*)0, 0, 0, LKK,
                    Vt, (long)DD * LKK, LKK, LKK,
                    1, 1.0f, (float*)0, 0, 0,
                    Rh, (long)LQ * DD, DD, (const float*)0,
                    (float*)0, invB, 0);
            } else {
                gemm_f16_nt<<<gS, blk, 0, stream>>>(
                    qcur, (long)LQ * DD, DD, (const _Float16*)0, 0, 0, DD,
                    Kh, (long)LKK * DD, DD, DD,
                    4, scale, S, (long)LQ * LKK, LKK,
                    (_Float16*)0, 0, 0, (const float*)0,
                    (float*)0, (const float*)0, 0);
                softmax_rows2<<<NB * LQ, blk, 0, stream>>>(S, attn2, 2048L, 1);
                gemm_f16_nt<<<gR, blk, 0, stream>>>(
                    attn2, (long)LQ * LKK, LKK,
                    (const _Float16*)0, 0, 0, LKK,
                    Vt, (long)DD * LKK, LKK, LKK,
                    1, 1.0f, (float*)0, 0, 0,
                    Rh, (long)LQ * DD, DD, (const float*)0,
                    (float*)0, (const float*)0, 0);
            }
            _Float16* qn = (h == 0) ? Qpong : (h == 1) ? Qping : (_Float16*)0;
            float* fo = (h == 2) ? Fout : (float*)0;
            gemm_f16_nt<<<gR, blk, 0, stream>>>(
                qcur, (long)LQ * DD, DD,
                Rh, (long)LQ * DD, DD, DD,
                Wh, 0, 2 * DD, 2 * DD,
                2, 1.0f, fo, (long)LQ * DD, DD,
                qn, (long)LQ * DD, DD, bias,
                (float*)0, (const float*)0, 0);
        }
        hipMemcpyAsync(d_out, Fout, 33554432ULL, hipMemcpyDeviceToDevice, stream);
    } else {
        // -------- round-1 f32 fallback --------
        float* outQ = (float*)d_out;
        float* S    = outQ + (size_t)NB * LQ * DD;
        float* R    = (float*)d_ws;
        float* T    = R + (size_t)NB * LQ * DD;
        dim3 gS(LKK / TN, LQ / TM, NB);
        dim3 gR(DD / TN, LQ / TM, NB);
        for (int h = 0; h < 3; ++h) {
            const float* Qh = (h == 0) ? Q : (h == 1 ? (const float*)T : (const float*)outQ);
            float* cout = (h == 1) ? outQ : T;
            gemm_nt_k<<<gS, blk, 0, stream>>>(Qh, DD, (long)LQ * DD, Km, DD, (long)LKK * DD,
                                              S, LKK, (long)LQ * LKK, DD, scale);
            softmax_rows<<<NB * LQ, blk, 0, stream>>>(S);
            gemm_nn_k<<<gR, blk, 0, stream>>>(S, LKK, (long)LQ * LKK, V, DD, (long)LKK * DD,
                                              R, DD, (long)LQ * DD, LKK);
            gemm_cat_k<<<gR, blk, 0, stream>>>(Qh, R, W, bias, cout);
        }
        hipMemcpyAsync(outQ, T, (size_t)NB * LQ * DD * sizeof(float),
                       hipMemcpyDeviceToDevice, stream);
    }
}

// Round 11
// 488.402 us; speedup vs baseline: 1.0043x; 1.0043x over previous
//
#include <hip/hip_runtime.h>
#include <math.h>

#define NB 16
#define LQ 512
#define LKK 2048
#define DD 1024

typedef _Float16 half8 __attribute__((ext_vector_type(8)));
typedef _Float16 half4 __attribute__((ext_vector_type(4)));
typedef float f32x4 __attribute__((ext_vector_type(4)));

__device__ __forceinline__ void gl_lds16(const void* g, void* l) {
    __builtin_amdgcn_global_load_lds(
        (const __attribute__((address_space(1))) void*)g,
        (__attribute__((address_space(3))) void*)l, 16, 0, 0);
}

// ===========================================================================
// 8-phase 256x256 NT-GEMM for QK^T  [proven R5-R10 — unchanged]
// ===========================================================================
__global__ __launch_bounds__(512, 2) void gemm_qk_256(
    const _Float16* __restrict__ A, long sA,
    const _Float16* __restrict__ B, long sB,
    _Float16* __restrict__ P, long sP,
    float* __restrict__ partial,
    float scale)
{
    __shared__ _Float16 lsA[2][256 * 64];
    __shared__ _Float16 lsB[2][256 * 64];
    const int tid = threadIdx.x;
    const int w = tid >> 6, l = tid & 63;
    const int wr = w >> 2, wc = w & 3;
    const int lrg = l >> 4, lc = l & 15, lr = lrg << 2;

    int id = blockIdx.x + gridDim.x * (blockIdx.y + gridDim.y * blockIdx.z);
    const int nwg = gridDim.x * gridDim.y * gridDim.z;
    id = (id & 7) * (nwg >> 3) + (id >> 3);
    const int bx = id % gridDim.x;
    const int t2 = id / gridDim.x;
    const int by = t2 % gridDim.y;
    const int z  = t2 / gridDim.y;
    const int m0 = by * 256, n0 = bx * 256;

    const _Float16* Ab = A + (size_t)z * sA + (size_t)m0 * DD;
    const _Float16* Bb = B + (size_t)z * sB + (size_t)n0 * DD;

    const int srow = l >> 3;
    const int sk = ((l & 7) ^ srow) << 3;

#define STG(dst, srcbase)                                                     \
    do {                                                                      \
        _Pragma("unroll")                                                     \
        for (int rr = 0; rr < 2; ++rr) {                                      \
            const int c = w + 8 * rr;                                         \
            gl_lds16((srcbase) + (size_t)(c * 8 + srow) * DD + sk,            \
                     (dst) + c * 512);                                        \
        }                                                                     \
    } while (0)

    half8 af[4][2], bf01[2][2], bf23[2][2];
    f32x4 acc[8][4] = {};
    const int rsb = (lc & 7) << 4;

#define LDA(buf, mh)                                                          \
    do {                                                                      \
        const char* p_ = (const char*)lsA[buf];                               \
        _Pragma("unroll")                                                     \
        for (int ii = 0; ii < 4; ++ii) {                                      \
            const int row_ = wr * 128 + (mh) * 64 + ii * 16 + lc;             \
            _Pragma("unroll")                                                 \
            for (int kk = 0; kk < 2; ++kk)                                    \
                af[ii][kk] = *(const half8*)(p_ + row_ * 128 +                \
                             ((kk * 64 + (lrg << 4)) ^ rsb));                 \
        }                                                                     \
    } while (0)

#define LDB(buf, nh, bfr)                                                     \
    do {                                                                      \
        const char* p_ = (const char*)lsB[buf];                               \
        _Pragma("unroll")                                                     \
        for (int jj = 0; jj < 2; ++jj) {                                      \
            const int row_ = wc * 64 + ((nh) * 2 + jj) * 16 + lc;             \
            _Pragma("unroll")                                                 \
            for (int kk = 0; kk < 2; ++kk)                                    \
                bfr[jj][kk] = *(const half8*)(p_ + row_ * 128 +               \
                              ((kk * 64 + (lrg << 4)) ^ rsb));                \
        }                                                                     \
    } while (0)

#define MM(mh, nh, bfr)                                                       \
    do {                                                                      \
        __builtin_amdgcn_s_setprio(1);                                        \
        _Pragma("unroll")                                                     \
        for (int ii = 0; ii < 4; ++ii)                                        \
            _Pragma("unroll")                                                 \
            for (int jj = 0; jj < 2; ++jj)                                    \
                _Pragma("unroll")                                             \
                for (int kk = 0; kk < 2; ++kk)                                \
                    acc[(mh) * 4 + ii][(nh) * 2 + jj] =                       \
                        __builtin_amdgcn_mfma_f32_16x16x32_f16(               \
                            af[ii][kk], bfr[jj][kk],                          \
                            acc[(mh) * 4 + ii][(nh) * 2 + jj], 0, 0, 0);      \
        __builtin_amdgcn_s_setprio(0);                                        \
    } while (0)

#define BAR __builtin_amdgcn_s_barrier()
#define VMW(n) asm volatile("s_waitcnt vmcnt(" #n ")" ::: "memory")

    STG(&lsA[0][0], Ab);
    STG(&lsA[0][128 * 64], Ab + (size_t)128 * DD);
    STG(&lsB[0][0], Bb);
    STG(&lsB[0][128 * 64], Bb + (size_t)128 * DD);
    STG(&lsA[1][0], Ab + 64);
    VMW(2);
    BAR;

    for (int i = 0; i < 7; ++i) {
        const int kt1 = (2 * i + 1) * 64, kt2 = kt1 + 64, kt3 = kt2 + 64;
        LDA(0, 0); LDB(0, 0, bf01);
        STG(&lsA[1][128 * 64], Ab + (size_t)128 * DD + kt1);
        BAR; MM(0, 0, bf01); BAR;
        LDB(0, 1, bf23);
        STG(&lsB[1][0], Bb + kt1);
        BAR; MM(0, 1, bf23); BAR;
        LDA(0, 1);
        STG(&lsB[1][128 * 64], Bb + (size_t)128 * DD + kt1);
        BAR; MM(1, 0, bf01); BAR;
        STG(&lsA[0][0], Ab + kt2);
        BAR; MM(1, 1, bf23);
        VMW(2); BAR;
        LDA(1, 0); LDB(1, 0, bf01);
        STG(&lsA[0][128 * 64], Ab + (size_t)128 * DD + kt2);
        BAR; MM(0, 0, bf01); BAR;
        LDB(1, 1, bf23);
        STG(&lsB[0][0], Bb + kt2);
        BAR; MM(0, 1, bf23); BAR;
        LDA(1, 1);
        STG(&lsB[0][128 * 64], Bb + (size_t)128 * DD + kt2);
        BAR; MM(1, 0, bf01); BAR;
        STG(&lsA[1][0], Ab + kt3);
        BAR; MM(1, 1, bf23);
        VMW(2); BAR;
    }
    {
        const int kt1 = 15 * 64;
        LDA(0, 0); LDB(0, 0, bf01);
        STG(&lsA[1][128 * 64], Ab + (size_t)128 * DD + kt1);
        BAR; MM(0, 0, bf01); BAR;
        LDB(0, 1, bf23);
        STG(&lsB[1][0], Bb + kt1);
        BAR; MM(0, 1, bf23); BAR;
        LDA(0, 1);
        STG(&lsB[1][128 * 64], Bb + (size_t)128 * DD + kt1);
        BAR; MM(1, 0, bf01); BAR;
        BAR; MM(1, 1, bf23);
        VMW(0); BAR;
        LDA(1, 0); LDB(1, 0, bf01);
        BAR; MM(0, 0, bf01); BAR;
        LDB(1, 1, bf23);
        BAR; MM(0, 1, bf23); BAR;
        LDA(1, 1);
        BAR; MM(1, 0, bf01); BAR;
        BAR; MM(1, 1, bf23);
    }
    __syncthreads();

    _Float16* Cb = P + (size_t)z * sP;
    float* psum = (float*)&lsA[0][0];
    #pragma unroll
    for (int i = 0; i < 8; ++i) {
        float rsum[4] = {0.f, 0.f, 0.f, 0.f};
        #pragma unroll
        for (int j = 0; j < 4; ++j) {
            const int n = n0 + wc * 64 + j * 16 + lc;
            #pragma unroll
            for (int r = 0; r < 4; ++r) {
                const int m = m0 + wr * 128 + i * 16 + lr + r;
                const float e = __expf(acc[i][j][r] * scale);
                Cb[(size_t)m * LKK + n] = (_Float16)e;
                rsum[r] += e;
            }
        }
        #pragma unroll
        for (int r = 0; r < 4; ++r) {
            float s = rsum[r];
            s += __shfl_xor(s, 1);
            s += __shfl_xor(s, 2);
            s += __shfl_xor(s, 4);
            s += __shfl_xor(s, 8);
            if (lc == 0) psum[(wr * 128 + i * 16 + lr + r) * 4 + wc] = s;
        }
    }
    __syncthreads();
    if (tid < 256) {
        const float* pr = psum + tid * 4;
        partial[((size_t)z * LQ + m0 + tid) * 8 + bx] = pr[0] + pr[1] + pr[2] + pr[3];
    }
#undef STG
#undef LDA
#undef LDB
#undef MM
}

// ===========================================================================
// 256x128 NT-GEMM for PV / cat — 4M x 2N waves, 3-buffer rolling schedule,
// counted vmcnt(6), 144KB LDS.  [proven R7-R10 — unchanged]
// ===========================================================================
__global__ __launch_bounds__(512, 2) void gemm_pc_256x128(
    const _Float16* __restrict__ Alo, long sAlo, int lda_lo,
    const _Float16* __restrict__ Ahi, long sAhi, int lda_hi,
    int ksplit,
    const _Float16* __restrict__ B, long sB, int ldb,
    int K, int mode,
    float* __restrict__ out32, long s32, int ldc32,
    _Float16* __restrict__ out16, long s16, int ldc16,
    const float* __restrict__ bias,
    const float* __restrict__ partial, int npart)
{
    __shared__ _Float16 ls[3][384 * 64];
    const int tid = threadIdx.x;
    const int w = tid >> 6, l = tid & 63;
    const int wr = w >> 1, wc = w & 1;     // 4M x 2N
    const int lrg = l >> 4, lc = l & 15, lr = lrg << 2;

    int id = blockIdx.x + gridDim.x * (blockIdx.y + gridDim.y * blockIdx.z);
    const int nwg = gridDim.x * gridDim.y * gridDim.z;
    id = (id & 7) * (nwg >> 3) + (id >> 3);
    const int bx = id % gridDim.x;
    const int t2_ = id / gridDim.x;
    const int by = t2_ % gridDim.y;
    const int z  = t2_ / gridDim.y;
    const int m0 = by * 256, n0 = bx * 128;

    const _Float16* Abase_lo = Alo + (size_t)z * sAlo + (size_t)m0 * lda_lo;
    const _Float16* Abase_hi = Ahi ? (Ahi + (size_t)z * sAhi + (size_t)m0 * lda_hi) : (const _Float16*)0;
    const _Float16* Bbase = B + (size_t)z * sB + (size_t)n0 * ldb;

    const int srow = l >> 3;
    const int sk = ((l & 7) ^ srow) << 3;
    const int rsb = (lc & 7) << 4;

    half8 af[4][2], bf[2][2];
    f32x4 acc[4][4] = {};

#define STGA(tt, dbuf)                                                        \
    do {                                                                      \
        const int kb_ = (tt) * 64;                                            \
        const _Float16* s_; int ld_;                                          \
        if (kb_ < ksplit) { s_ = Abase_lo + kb_;           ld_ = lda_lo; }    \
        else              { s_ = Abase_hi + (kb_ - ksplit); ld_ = lda_hi; }   \
        _Float16* d_ = &ls[dbuf][0];                                          \
        _Pragma("unroll")                                                     \
        for (int rr = 0; rr < 4; ++rr) {                                      \
            const int c = w + 8 * rr;                                         \
            gl_lds16(s_ + (size_t)(c * 8 + srow) * ld_ + sk, d_ + c * 512);   \
        }                                                                     \
    } while (0)

#define STGB(tt, dbuf)                                                        \
    do {                                                                      \
        const _Float16* s_ = Bbase + (tt) * 64;                               \
        _Float16* d_ = &ls[dbuf][256 * 64];                                   \
        _Pragma("unroll")                                                     \
        for (int rr = 0; rr < 2; ++rr) {                                      \
            const int c = w + 8 * rr;                                         \
            gl_lds16(s_ + (size_t)(c * 8 + srow) * ldb + sk, d_ + c * 512);   \
        }                                                                     \
    } while (0)

#define LDA2(buf)                                                             \
    do {                                                                      \
        const char* p_ = (const char*)&ls[buf][0];                            \
        _Pragma("unroll")                                                     \
        for (int ii = 0; ii < 4; ++ii) {                                      \
            const int row_ = wr * 64 + ii * 16 + lc;                          \
            _Pragma("unroll")                                                 \
            for (int kk = 0; kk < 2; ++kk)                                    \
                af[ii][kk] = *(const half8*)(p_ + row_ * 128 +                \
                             ((kk * 64 + (lrg << 4)) ^ rsb));                 \
        }                                                                     \
    } while (0)

#define LDB2(buf, nh)                                                         \
    do {                                                                      \
        const char* p_ = (const char*)&ls[buf][256 * 64];                     \
        _Pragma("unroll")                                                     \
        for (int jj = 0; jj < 2; ++jj) {                                      \
            const int row_ = wc * 64 + ((nh) * 2 + jj) * 16 + lc;             \
            _Pragma("unroll")                                                 \
            for (int kk = 0; kk < 2; ++kk)                                    \
                bf[jj][kk] = *(const half8*)(p_ + row_ * 128 +                \
                              ((kk * 64 + (lrg << 4)) ^ rsb));                \
        }                                                                     \
    } while (0)

#define MM2(nh)                                                               \
    do {                                                                      \
        __builtin_amdgcn_s_setprio(1);                                        \
        _Pragma("unroll")                                                     \
        for (int ii = 0; ii < 4; ++ii)                                        \
            _Pragma("unroll")                                                 \
            for (int jj = 0; jj < 2; ++jj)                                    \
                _Pragma("unroll")                                             \
                for (int kk = 0; kk < 2; ++kk)                                \
                    acc[ii][(nh) * 2 + jj] =                                  \
                        __builtin_amdgcn_mfma_f32_16x16x32_f16(               \
                            af[ii][kk], bf[jj][kk],                           \
                            acc[ii][(nh) * 2 + jj], 0, 0, 0);                 \
        __builtin_amdgcn_s_setprio(0);                                        \
    } while (0)

    const int NT = K >> 6;
    STGA(0, 0); STGB(0, 0);
    STGA(1, 1); STGB(1, 1);
    VMW(6);
    BAR;

    int b = 0, b2 = 2;
    for (int t = 0; t < NT; ++t) {
        const int tt = t + 2;
        const bool st = tt < NT;
        LDA2(b); LDB2(b, 0);
        if (st) STGA(tt, b2);
        BAR; MM2(0); BAR;
        LDB2(b, 1);
        if (st) STGB(tt, b2);
        BAR; MM2(1);
        if (t < NT - 2)       VMW(6);
        else if (t == NT - 2) VMW(0);
        BAR;
        b = (b == 2) ? 0 : b + 1;
        b2 = (b2 == 2) ? 0 : b2 + 1;
    }
    __syncthreads();

    if (mode == 1) {
        float* psum = (float*)&ls[0][0];
        if (tid < 256) {
            const float* pp = partial + ((size_t)z * LQ + m0 + tid) * npart;
            float s = 0.0f;
            for (int c = 0; c < npart; ++c) s += pp[c];
            psum[tid] = 1.0f / s;
        }
        __syncthreads();
        _Float16* Cb = out16 + (size_t)z * s16;
        #pragma unroll
        for (int i = 0; i < 4; ++i)
            #pragma unroll
            for (int j = 0; j < 4; ++j) {
                const int n = n0 + wc * 64 + j * 16 + lc;
                #pragma unroll
                for (int r = 0; r < 4; ++r) {
                    const int ml = wr * 64 + i * 16 + lr + r;
                    Cb[(size_t)(m0 + ml) * ldc16 + n] =
                        (_Float16)(acc[i][j][r] * psum[ml]);
                }
            }
    } else {
        float bv[4];
        #pragma unroll
        for (int j = 0; j < 4; ++j)
            bv[j] = bias[n0 + wc * 64 + j * 16 + lc];
        #pragma unroll
        for (int i = 0; i < 4; ++i)
            #pragma unroll
            for (int j = 0; j < 4; ++j) {
                const int n = n0 + wc * 64 + j * 16 + lc;
                #pragma unroll
                for (int r = 0; r < 4; ++r) {
                    const int m = m0 + wr * 64 + i * 16 + lr + r;
                    const float t = tanhf(acc[i][j][r] + bv[j]);
                    if (out16) out16[(size_t)z * s16 + (size_t)m * ldc16 + n] = (_Float16)t;
                    if (out32) out32[(size_t)z * s32 + (size_t)m * ldc32 + n] = t;
                }
            }
    }
#undef STGA
#undef STGB
#undef LDA2
#undef LDB2
#undef MM2
#undef BAR
#undef VMW
}

// ---------------------------------------------------------------------------
// f16 MFMA NT-GEMM 128x128 (R3-fallback path only)
// ---------------------------------------------------------------------------
__global__ __launch_bounds__(256) void gemm_f16_nt(
    const _Float16* __restrict__ Alo, long sAlo, int lda_lo,
    const _Float16* __restrict__ Ahi, long sAhi, int lda_hi,
    int ksplit,
    const _Float16* __restrict__ B, long sB, int ldb,
    int K, int mode, float scale,
    float* __restrict__ out32, long s32, int ldc32,
    _Float16* __restrict__ out16, long s16, int ldc16,
    const float* __restrict__ bias,
    float* __restrict__ partial, const float* __restrict__ inv, int npart)
{
    __shared__ _Float16 lsA[128 * 64];
    __shared__ _Float16 lsB[128 * 64];
    __shared__ float psum[128][2];
    const int tid = threadIdx.x;
    const int w = tid >> 6, l = tid & 63;
    const int wr = w >> 1, wc = w & 1;

    int id = blockIdx.x + gridDim.x * (blockIdx.y + gridDim.y * blockIdx.z);
    const int nwg = gridDim.x * gridDim.y * gridDim.z;
    id = (id & 7) * (nwg >> 3) + (id >> 3);
    const int bx = id % gridDim.x;
    const int t2 = id / gridDim.x;
    const int by = t2 % gridDim.y;
    const int z = t2 / gridDim.y;
    const int m0 = by * 128, n0 = bx * 128;

    const _Float16* Abase_lo = Alo + (size_t)z * sAlo + (size_t)m0 * lda_lo;
    const _Float16* Abase_hi = Ahi ? (Ahi + (size_t)z * sAhi + (size_t)m0 * lda_hi) : (const _Float16*)0;
    const _Float16* Bbase = B + (size_t)z * sB + (size_t)n0 * ldb;

    const int srow = l >> 3;
    const int sswz = ((l & 7) ^ srow) << 3;

    f32x4 acc[4][4] = {};

    for (int k0 = 0; k0 < K; k0 += 64) {
        const _Float16* Ap; int kloc, ldaA;
        if (k0 < ksplit) { Ap = Abase_lo; kloc = k0;          ldaA = lda_lo; }
        else             { Ap = Abase_hi; kloc = k0 - ksplit; ldaA = lda_hi; }
        #pragma unroll
        for (int i = 0; i < 4; ++i) {
            const int c = w * 4 + i;
            const int row = c * 8 + srow;
            gl_lds16(Ap + (size_t)row * ldaA + kloc + sswz, &lsA[c * 512]);
        }
        #pragma unroll
        for (int i = 0; i < 4; ++i) {
            const int c = w * 4 + i;
            const int row = c * 8 + srow;
            gl_lds16(Bbase + (size_t)row * ldb + k0 + sswz, &lsB[c * 512]);
        }
        __syncthreads();

        half8 af[4][2], bf[4][2];
        const char* lA = (const char*)lsA;
        const char* lB = (const char*)lsB;
        const int rs = (l & 7) << 4;
        const int cb = (l >> 4) << 4;
        #pragma unroll
        for (int i = 0; i < 4; ++i) {
            const int rowa = wr * 64 + i * 16 + (l & 15);
            const int rowb = wc * 64 + i * 16 + (l & 15);
            #pragma unroll
            for (int kk = 0; kk < 2; ++kk) {
                af[i][kk] = *(const half8*)(lA + rowa * 128 + ((kk * 64 + cb) ^ rs));
                bf[i][kk] = *(const half8*)(lB + rowb * 128 + ((kk * 64 + cb) ^ rs));
            }
        }
        #pragma unroll
        for (int kk = 0; kk < 2; ++kk)
            #pragma unroll
            for (int i = 0; i < 4; ++i)
                #pragma unroll
                for (int j = 0; j < 4; ++j)
                    acc[i][j] = __builtin_amdgcn_mfma_f32_16x16x32_f16(
                        af[i][kk], bf[j][kk], acc[i][j], 0, 0, 0);
        __syncthreads();
    }

    const int lr = (l >> 4) * 4;
    const int lc = l & 15;
    if (mode == 0) {
        _Float16* Cb = out16 + (size_t)z * s16;
        float rsum[4][4];
        #pragma unroll
        for (int i = 0; i < 4; ++i)
            #pragma unroll
            for (int r = 0; r < 4; ++r) rsum[i][r] = 0.0f;
        #pragma unroll
        for (int i = 0; i < 4; ++i)
            #pragma unroll
            for (int j = 0; j < 4; ++j) {
                const int n = n0 + wc * 64 + j * 16 + lc;
                #pragma unroll
                for (int r = 0; r < 4; ++r) {
                    const int m = m0 + wr * 64 + i * 16 + lr + r;
                    const float e = __expf(acc[i][j][r] * scale);
                    Cb[(size_t)m * ldc16 + n] = (_Float16)e;
                    rsum[i][r] += e;
                }
            }
        #pragma unroll
        for (int i = 0; i < 4; ++i)
            #pragma unroll
            for (int r = 0; r < 4; ++r) {
                float s = rsum[i][r];
                s += __shfl_xor(s, 1);
                s += __shfl_xor(s, 2);
                s += __shfl_xor(s, 4);
                s += __shfl_xor(s, 8);
                rsum[i][r] = s;
            }
        if (lc == 0) {
            #pragma unroll
            for (int i = 0; i < 4; ++i)
                #pragma unroll
                for (int r = 0; r < 4; ++r)
                    psum[wr * 64 + i * 16 + lr + r][wc] = rsum[i][r];
        }
        __syncthreads();
        if (tid < 128)
            partial[((size_t)z * LQ + m0 + tid) * npart + bx] = psum[tid][0] + psum[tid][1];
    } else if (mode == 1) {
        _Float16* Cb = out16 + (size_t)z * s16;
        float iv[4][4];
        if (partial) {
            if (tid < 128) {
                const float* pp = partial + ((size_t)z * LQ + m0 + tid) * npart;
                float s = 0.0f;
                for (int c = 0; c < npart; ++c) s += pp[c];
                psum[tid][0] = 1.0f / s;
            }
            __syncthreads();
            #pragma unroll
            for (int i = 0; i < 4; ++i)
                #pragma unroll
                for (int r = 0; r < 4; ++r)
                    iv[i][r] = psum[wr * 64 + i * 16 + lr + r][0];
        } else {
            #pragma unroll
            for (int i = 0; i < 4; ++i)
                #pragma unroll
                for (int r = 0; r < 4; ++r)
                    iv[i][r] = inv ? inv[(size_t)z * LQ + m0 + wr * 64 + i * 16 + lr + r] : 1.0f;
        }
        #pragma unroll
        for (int i = 0; i < 4; ++i)
            #pragma unroll
            for (int j = 0; j < 4; ++j) {
                const int n = n0 + wc * 64 + j * 16 + lc;
                #pragma unroll
                for (int r = 0; r < 4; ++r) {
                    const int m = m0 + wr * 64 + i * 16 + lr + r;
                    Cb[(size_t)m * ldc16 + n] = (_Float16)(acc[i][j][r] * iv[i][r]);
                }
            }
    } else if (mode == 4) {
        float* Cb = out32 + (size_t)z * s32;
        #pragma unroll
        for (int i = 0; i < 4; ++i)
            #pragma unroll
            for (int j = 0; j < 4; ++j) {
                const int n = n0 + wc * 64 + j * 16 + lc;
                #pragma unroll
                for (int r = 0; r < 4; ++r) {
                    const int m = m0 + wr * 64 + i * 16 + lr + r;
                    Cb[(size_t)m * ldc32 + n] = acc[i][j][r] * scale;
                }
            }
    } else {
        float bv[4];
        #pragma unroll
        for (int j = 0; j < 4; ++j)
            bv[j] = bias[n0 + wc * 64 + j * 16 + lc];
        #pragma unroll
        for (int i = 0; i < 4; ++i)
            #pragma unroll
            for (int j = 0; j < 4; ++j) {
                const int n = n0 + wc * 64 + j * 16 + lc;
                #pragma unroll
                for (int r = 0; r < 4; ++r) {
                    const int m = m0 + wr * 64 + i * 16 + lr + r;
                    const float t = tanhf(acc[i][j][r] + bv[j]);
                    if (out16) out16[(size_t)z * s16 + (size_t)m * ldc16 + n] = (_Float16)t;
                    if (out32) out32[(size_t)z * s32 + (size_t)m * ldc32 + n] = t;
                }
            }
    }
}

// one block per row: attn_f32[row,:] = P16[row,:] * (1/sum partial[row,0..npart))
__global__ __launch_bounds__(256) void scale_attn(
    const _Float16* __restrict__ P, const float* __restrict__ partial,
    float* __restrict__ attn, int npart)
{
    __shared__ float sinv;
    const long row = blockIdx.x;
    const int tid = threadIdx.x;
    if (tid < npart) {
        float s = partial[row * npart + tid];
        for (int off = npart >> 1; off > 0; off >>= 1) s += __shfl_xor(s, off);
        if (tid == 0) sinv = 1.0f / s;
    }
    __syncthreads();
    const float inv = sinv;
    const half8 h = *(const half8*)(P + row * 2048 + tid * 8);
    float* o = attn + row * 2048 + tid * 8;
    float4 a = make_float4((float)h[0] * inv, (float)h[1] * inv,
                           (float)h[2] * inv, (float)h[3] * inv);
    float4 b = make_float4((float)h[4] * inv, (float)h[5] * inv,
                           (float)h[6] * inv, (float)h[7] * inv);
    *(float4*)o = a;
    *(float4*)(o + 4) = b;
}

// inv[row] = 1 / sum_{cb<16} partial[row*16+cb]   (R3-fallback path)
__global__ __launch_bounds__(256) void make_inv(
    const float* __restrict__ partial, float* __restrict__ inv)
{
    const int row = blockIdx.x * 256 + threadIdx.x;
    const float4 a = *(const float4*)(partial + (size_t)row * 16);
    const float4 b = *(const float4*)(partial + (size_t)row * 16 + 4);
    const float4 c = *(const float4*)(partial + (size_t)row * 16 + 8);
    const float4 d = *(const float4*)(partial + (size_t)row * 16 + 12);
    const float s = (a.x + a.y + a.z + a.w) + (b.x + b.y + b.z + b.w)
                  + (c.x + c.y + c.z + c.w) + (d.x + d.y + d.z + d.w);
    inv[row] = 1.0f / s;
}

// row softmax over 2048 f32 (R3-fallback hop 2)
__global__ __launch_bounds__(256) void softmax_rows2(
    float* __restrict__ S, _Float16* __restrict__ f16out,
    long f16stride, int write_f32)
{
    __shared__ float red[8];
    const long row = blockIdx.x;
    float* p = S + row * LKK;
    const int tid = threadIdx.x;
    float4 v0 = ((const float4*)p)[tid];
    float4 v1 = ((const float4*)p)[tid + 256];
    float m = fmaxf(fmaxf(fmaxf(v0.x, v0.y), fmaxf(v0.z, v0.w)),
                    fmaxf(fmaxf(v1.x, v1.y), fmaxf(v1.z, v1.w)));
    #pragma unroll
    for (int off = 32; off > 0; off >>= 1) m = fmaxf(m, __shfl_down(m, off));
    if ((tid & 63) == 0) red[tid >> 6] = m;
    __syncthreads();
    m = fmaxf(fmaxf(red[0], red[1]), fmaxf(red[2], red[3]));
    v0.x = expf(v0.x - m); v0.y = expf(v0.y - m);
    v0.z = expf(v0.z - m); v0.w = expf(v0.w - m);
    v1.x = expf(v1.x - m); v1.y = expf(v1.y - m);
    v1.z = expf(v1.z - m); v1.w = expf(v1.w - m);
    float s = v0.x + v0.y + v0.z + v0.w + v1.x + v1.y + v1.z + v1.w;
    #pragma unroll
    for (int off = 32; off > 0; off >>= 1) s += __shfl_down(s, off);
    if ((tid & 63) == 0) red[4 + (tid >> 6)] = s;
    __syncthreads();
    s = red[4] + red[5] + red[6] + red[7];
    const float inv = 1.0f / s;
    v0.x *= inv; v0.y *= inv; v0.z *= inv; v0.w *= inv;
    v1.x *= inv; v1.y *= inv; v1.z *= inv; v1.w *= inv;
    if (write_f32) {
        ((float4*)p)[tid] = v0;
        ((float4*)p)[tid + 256] = v1;
    }
    _Float16* q = f16out + row * f16stride;
    half4 h0 = { (_Float16)v0.x, (_Float16)v0.y, (_Float16)v0.z, (_Float16)v0.w };
    half4 h1 = { (_Float16)v1.x, (_Float16)v1.y, (_Float16)v1.z, (_Float16)v1.w };
    *(half4*)(q + tid * 4) = h0;
    *(half4*)(q + 1024 + tid * 4) = h1;
}

__global__ __launch_bounds__(256) void cvt_f32_to_f16(
    const float* __restrict__ in, _Float16* __restrict__ out, long n)
{
    const long i = ((long)blockIdx.x * 256 + threadIdx.x) * 8;
    if (i + 8 > n) return;
    float4 a = *(const float4*)(in + i);
    float4 b = *(const float4*)(in + i + 4);
    half8 h = { (_Float16)a.x, (_Float16)a.y, (_Float16)a.z, (_Float16)a.w,
                (_Float16)b.x, (_Float16)b.y, (_Float16)b.z, (_Float16)b.w };
    *(half8*)(out + i) = h;
}

// V [B, Lk, D] f32 -> Vt [B, D, Lk] f16, 64x64 tiles via LDS (fallback paths)
__global__ __launch_bounds__(256) void transpose_cvt_v(
    const float* __restrict__ V, _Float16* __restrict__ Vt)
{
    __shared__ _Float16 t[64][80];
    const int z = blockIdx.z;
    const int k0 = blockIdx.y * 64, d0 = blockIdx.x * 64;
    const float* Vb = V + (size_t)z * LKK * DD;
    _Float16* Vtb = Vt + (size_t)z * DD * LKK;
    const int r = threadIdx.x >> 2;
    const int c0 = (threadIdx.x & 3) * 16;
    #pragma unroll
    for (int j = 0; j < 4; ++j) {
        float4 v = *(const float4*)(Vb + (size_t)(k0 + r) * DD + d0 + c0 + j * 4);
        t[c0 + j * 4 + 0][r] = (_Float16)v.x;
        t[c0 + j * 4 + 1][r] = (_Float16)v.y;
        t[c0 + j * 4 + 2][r] = (_Float16)v.z;
        t[c0 + j * 4 + 3][r] = (_Float16)v.w;
    }
    __syncthreads();
    #pragma unroll
    for (int j = 0; j < 2; ++j) {
        half8 h = *(const half8*)&t[r][c0 + j * 8];
        *(half8*)(Vtb + (size_t)(d0 + r) * LKK + k0 + c0 + j * 8) = h;
    }
}

// ===========================================================================
// R11 prep: every memory instruction fully lane-dense.
//   cvt blocks [0,5376): 8 passes; loads lane-contiguous float4 (1KB/wave),
//     stores lane-contiguous half4 (512B/wave). All 8 loads before stores.
//   V-transpose blocks [5376,9472): reads 16-lane-contiguous (256B rows,
//     4 rows/instr); writes 4-lane-contiguous half8 (64B dense); pad 82.
// ===========================================================================
__global__ __launch_bounds__(256) void prep_all(
    const float* __restrict__ Q, const float* __restrict__ K,
    const float* __restrict__ W, const float* __restrict__ V,
    _Float16* __restrict__ Qh, _Float16* __restrict__ Kh,
    _Float16* __restrict__ Wh, _Float16* __restrict__ Vt)
{
    __shared__ _Float16 t[64][82];
    const int b = blockIdx.x;
    const int tid = threadIdx.x;

    if (b < 5376) {
        const float* src; _Float16* dst; long bloc;
        if (b < 1024)      { src = Q; dst = Qh; bloc = b; }
        else if (b < 5120) { src = K; dst = Kh; bloc = b - 1024; }
        else               { src = W; dst = Wh; bloc = b - 5120; }
        const float4* F = (const float4*)src + bloc * 2048;
        half4* H = (half4*)dst + bloc * 2048;
        float4 v[8];
        #pragma unroll
        for (int c = 0; c < 8; ++c) v[c] = F[c * 256 + tid];
        #pragma unroll
        for (int c = 0; c < 8; ++c) {
            half4 h = { (_Float16)v[c].x, (_Float16)v[c].y,
                        (_Float16)v[c].z, (_Float16)v[c].w };
            H[c * 256 + tid] = h;
        }
        return;
    }
    // V transpose: bb in [0,4096): dx 16 x ky2 16 x z 16; 2 k-tiles per block
    const int bb = b - 5376;
    const int dx  = bb & 15;
    const int ky2 = (bb >> 4) & 15;
    const int z   = bb >> 8;
    const int d0 = dx * 64;
    const float* Vb = V + (size_t)z * LKK * DD;
    _Float16* Vtb = Vt + (size_t)z * DD * LKK;
    const int rr = tid >> 4;          // 0..15 (k-row within pass)
    const int cc = (tid & 15) * 4;    // 0..60 (d-col, 16-lane contiguous)
    const int ro = tid >> 2;          // 0..63 (output d-row)
    const int co = (tid & 3) * 8;     // 0..24 (k-col, 4-lane dense half8)
    for (int half = 0; half < 2; ++half) {
        const int k0 = (ky2 * 2 + half) * 64;
        float4 v[4];
        #pragma unroll
        for (int p = 0; p < 4; ++p)
            v[p] = *(const float4*)(Vb + (size_t)(k0 + p * 16 + rr) * DD + d0 + cc);
        #pragma unroll
        for (int p = 0; p < 4; ++p) {
            t[cc + 0][p * 16 + rr] = (_Float16)v[p].x;
            t[cc + 1][p * 16 + rr] = (_Float16)v[p].y;
            t[cc + 2][p * 16 + rr] = (_Float16)v[p].z;
            t[cc + 3][p * 16 + rr] = (_Float16)v[p].w;
        }
        __syncthreads();
        #pragma unroll
        for (int j = 0; j < 2; ++j) {
            half8 h = *(const half8*)&t[ro][co + j * 32];
            *(half8*)(Vtb + (size_t)(d0 + ro) * LKK + k0 + co + j * 32) = h;
        }
        __syncthreads();
    }
}

// ======================= round-1 f32 fallback kernels =======================
constexpr int TM = 64, TN = 64, TK = 32;
constexpr int PAD = 4;

__global__ __launch_bounds__(256) void gemm_nt_k(
    const float* __restrict__ A, int lda, long sA,
    const float* __restrict__ Bt, int ldb, long sB,
    float* __restrict__ C, int ldc, long sC, int K, float scale)
{
    __shared__ float As[TK][TM + PAD];
    __shared__ float Bs[TK][TN + PAD];
    const float* Ab = A + (long)blockIdx.z * sA;
    const float* Bb = Bt + (long)blockIdx.z * sB;
    float* Cb = C + (long)blockIdx.z * sC;
    const int m0 = blockIdx.y * TM, n0 = blockIdx.x * TN;
    const int tid = threadIdx.x;
    const int tn = tid & 15, tm = tid >> 4;
    float acc[4][4] = {};
    for (int k0 = 0; k0 < K; k0 += TK) {
        #pragma unroll
        for (int c = tid; c < (TM * TK) / 4; c += 256) {
            const int row = c >> 3, kc = (c & 7) << 2;
            const float4 g = *(const float4*)(Ab + (long)(m0 + row) * lda + (k0 + kc));
            As[kc + 0][row] = g.x; As[kc + 1][row] = g.y;
            As[kc + 2][row] = g.z; As[kc + 3][row] = g.w;
        }
        #pragma unroll
        for (int c = tid; c < (TN * TK) / 4; c += 256) {
            const int row = c >> 3, kc = (c & 7) << 2;
            const float4 g = *(const float4*)(Bb + (long)(n0 + row) * ldb + (k0 + kc));
            Bs[kc + 0][row] = g.x; Bs[kc + 1][row] = g.y;
            Bs[kc + 2][row] = g.z; Bs[kc + 3][row] = g.w;
        }
        __syncthreads();
        #pragma unroll
        for (int kk = 0; kk < TK; ++kk) {
            const float4 av = *(const float4*)&As[kk][tm << 2];
            const float4 bv = *(const float4*)&Bs[kk][tn << 2];
            const float a[4] = {av.x, av.y, av.z, av.w};
            const float b[4] = {bv.x, bv.y, bv.z, bv.w};
            #pragma unroll
            for (int i = 0; i < 4; ++i)
                #pragma unroll
                for (int j = 0; j < 4; ++j)
                    acc[i][j] = fmaf(a[i], b[j], acc[i][j]);
        }
        __syncthreads();
    }
    #pragma unroll
    for (int i = 0; i < 4; ++i) {
        float4 o = make_float4(acc[i][0] * scale, acc[i][1] * scale,
                               acc[i][2] * scale, acc[i][3] * scale);
        *(float4*)(Cb + (long)(m0 + (tm << 2) + i) * ldc + n0 + (tn << 2)) = o;
    }
}

__global__ __launch_bounds__(256) void gemm_nn_k(
    const float* __restrict__ A, int lda, long sA,
    const float* __restrict__ B, int ldb, long sB,
    float* __restrict__ C, int ldc, long sC, int K)
{
    __shared__ float As[TK][TM + PAD];
    __shared__ float Bs[TK][TN + PAD];
    const float* Ab = A + (long)blockIdx.z * sA;
    const float* Bb = B + (long)blockIdx.z * sB;
    float* Cb = C + (long)blockIdx.z * sC;
    const int m0 = blockIdx.y * TM, n0 = blockIdx.x * TN;
    const int tid = threadIdx.x;
    const int tn = tid & 15, tm = tid >> 4;
    float acc[4][4] = {};
    for (int k0 = 0; k0 < K; k0 += TK) {
        #pragma unroll
        for (int c = tid; c < (TM * TK) / 4; c += 256) {
            const int row = c >> 3, kc = (c & 7) << 2;
            const float4 g = *(const float4*)(Ab + (long)(m0 + row) * lda + (k0 + kc));
            As[kc + 0][row] = g.x; As[kc + 1][row] = g.y;
            As[kc + 2][row] = g.z; As[kc + 3][row] = g.w;
        }
        #pragma unroll
        for (int c = tid; c < (TK * TN) / 4; c += 256) {
            const int krow = c >> 4, nc = (c & 15) << 2;
            *(float4*)&Bs[krow][nc] =
                *(const float4*)(Bb + (long)(k0 + krow) * ldb + n0 + nc);
        }
        __syncthreads();
        #pragma unroll
        for (int kk = 0; kk < TK; ++kk) {
            const float4 av = *(const float4*)&As[kk][tm << 2];
            const float4 bv = *(const float4*)&Bs[kk][tn << 2];
            const float a[4] = {av.x, av.y, av.z, av.w};
            const float b[4] = {bv.x, bv.y, bv.z, bv.w};
            #pragma unroll
            for (int i = 0; i < 4; ++i)
                #pragma unroll
                for (int j = 0; j < 4; ++j)
                    acc[i][j] = fmaf(a[i], b[j], acc[i][j]);
        }
        __syncthreads();
    }
    #pragma unroll
    for (int i = 0; i < 4; ++i) {
        float4 o = make_float4(acc[i][0], acc[i][1], acc[i][2], acc[i][3]);
        *(float4*)(Cb + (long)(m0 + (tm << 2) + i) * ldc + n0 + (tn << 2)) = o;
    }
}

__global__ __launch_bounds__(256) void gemm_cat_k(
    const float* __restrict__ Qh, const float* __restrict__ R,
    const float* __restrict__ W, const float* __restrict__ bias,
    float* __restrict__ C)
{
    __shared__ float As[TK][TM + PAD];
    __shared__ float Bs[TK][TN + PAD];
    const float* Qb = Qh + (long)blockIdx.z * LQ * DD;
    const float* Rb = R + (long)blockIdx.z * LQ * DD;
    float* Cb = C + (long)blockIdx.z * LQ * DD;
    const int m0 = blockIdx.y * TM, n0 = blockIdx.x * TN;
    const int tid = threadIdx.x;
    const int tn = tid & 15, tm = tid >> 4;
    float acc[4][4] = {};
    for (int k0 = 0; k0 < 2 * DD; k0 += TK) {
        const float* src = (k0 < DD) ? Qb : Rb;
        const int kb = (k0 < DD) ? k0 : k0 - DD;
        #pragma unroll
        for (int c = tid; c < (TM * TK) / 4; c += 256) {
            const int row = c >> 3, kc = (c & 7) << 2;
            const float4 g = *(const float4*)(src + (long)(m0 + row) * DD + (kb + kc));
            As[kc + 0][row] = g.x; As[kc + 1][row] = g.y;
            As[kc + 2][row] = g.z; As[kc + 3][row] = g.w;
        }
        #pragma unroll
        for (int c = tid; c < (TN * TK) / 4; c += 256) {
            const int row = c >> 3, kc = (c & 7) << 2;
            const float4 g = *(const float4*)(W + (long)(n0 + row) * (2 * DD) + (k0 + kc));
            Bs[kc + 0][row] = g.x; Bs[kc + 1][row] = g.y;
            Bs[kc + 2][row] = g.z; Bs[kc + 3][row] = g.w;
        }
        __syncthreads();
        #pragma unroll
        for (int kk = 0; kk < TK; ++kk) {
            const float4 av = *(const float4*)&As[kk][tm << 2];
            const float4 bv = *(const float4*)&Bs[kk][tn << 2];
            const float a[4] = {av.x, av.y, av.z, av.w};
            const float b[4] = {bv.x, bv.y, bv.z, bv.w};
            #pragma unroll
            for (int i = 0; i < 4; ++i)
                #pragma unroll
                for (int j = 0; j < 4; ++j)
                    acc[i][j] = fmaf(a[i], b[j], acc[i][j]);
        }
        __syncthreads();
    }
    #pragma unroll
    for (int i = 0; i < 4; ++i) {
        float4 o;
        o.x = tanhf(acc[i][0] + bias[n0 + (tn << 2) + 0]);
        o.y = tanhf(acc[i][1] + bias[n0 + (tn << 2) + 1]);
        o.z = tanhf(acc[i][2] + bias[n0 + (tn << 2) + 2]);
        o.w = tanhf(acc[i][3] + bias[n0 + (tn << 2) + 3]);
        *(float4*)(Cb + (long)(m0 + (tm << 2) + i) * DD + n0 + (tn << 2)) = o;
    }
}

__global__ __launch_bounds__(256) void softmax_rows(float* __restrict__ S) {
    __shared__ float red[8];
    float* p = S + (size_t)blockIdx.x * LKK;
    const int tid = threadIdx.x;
    float4 v0 = ((const float4*)p)[tid];
    float4 v1 = ((const float4*)p)[tid + 256];
    float m = fmaxf(fmaxf(fmaxf(v0.x, v0.y), fmaxf(v0.z, v0.w)),
                    fmaxf(fmaxf(v1.x, v1.y), fmaxf(v1.z, v1.w)));
    #pragma unroll
    for (int off = 32; off > 0; off >>= 1) m = fmaxf(m, __shfl_down(m, off));
    if ((tid & 63) == 0) red[tid >> 6] = m;
    __syncthreads();
    m = fmaxf(fmaxf(red[0], red[1]), fmaxf(red[2], red[3]));
    v0.x = expf(v0.x - m); v0.y = expf(v0.y - m);
    v0.z = expf(v0.z - m); v0.w = expf(v0.w - m);
    v1.x = expf(v1.x - m); v1.y = expf(v1.y - m);
    v1.z = expf(v1.z - m); v1.w = expf(v1.w - m);
    float s = v0.x + v0.y + v0.z + v0.w + v1.x + v1.y + v1.z + v1.w;
    #pragma unroll
    for (int off = 32; off > 0; off >>= 1) s += __shfl_down(s, off);
    if ((tid & 63) == 0) red[4 + (tid >> 6)] = s;
    __syncthreads();
    s = red[4] + red[5] + red[6] + red[7];
    const float inv = 1.0f / s;
    v0.x *= inv; v0.y *= inv; v0.z *= inv; v0.w *= inv;
    v1.x *= inv; v1.y *= inv; v1.z *= inv; v1.w *= inv;
    ((float4*)p)[tid] = v0;
    ((float4*)p)[tid + 256] = v1;
}

// ===========================================================================
extern "C" void kernel_launch(void* const* d_in, const int* in_sizes, int n_in,
                              void* d_out, int out_size, void* d_ws, size_t ws_size,
                              hipStream_t stream) {
    const float* Q    = (const float*)d_in[0];
    const float* Km   = (const float*)d_in[1];
    const float* V    = (const float*)d_in[2];
    const float* W    = (const float*)d_in[3];
    const float* bias = (const float*)d_in[4];
    const float scale = 0.03125f;  // 1/sqrt(1024)
    dim3 blk(256);

    const size_t NEED_FULL = 189267968ULL;
    const size_t NEED_R3   = 155189248ULL;

    if (ws_size >= NEED_FULL) {
        char* ws = (char*)d_ws;
        _Float16* Kh     = (_Float16*)ws;                    // [16,2048,1024]
        _Float16* Vt     = (_Float16*)(ws + 67108864);       // [16,1024,2048]
        _Float16* Wh     = (_Float16*)(ws + 134217728);      // [1024,2048]
        _Float16* Rh     = (_Float16*)(ws + 138412032);      // [16,512,1024]
        _Float16* Qping  = (_Float16*)(ws + 155189248);      // [16,512,1024]
        _Float16* Qpong  = (_Float16*)(ws + 171966464);      // [16,512,1024]
        float*    partialB = (float*)(ws + 188743680);       // [8192,8]

        float*    outQ  = (float*)d_out;
        _Float16* P2    = (_Float16*)d_out;
        float*    attnF = (float*)((char*)d_out + 33554432);
        _Float16* P01   = (_Float16*)attnF;

        // R11: dense-instruction single prep dispatch
        prep_all<<<9472, blk, 0, stream>>>(Q, Km, W, V, Qping, Kh, Wh, Vt);

        dim3 gS2(LKK / 256, LQ / 256, NB);  // 8 x 2 x 16 = 256 blocks
        dim3 gP(DD / 128, LQ / 256, NB);    // 8 x 2 x 16 = 256 blocks

        for (int h = 0; h < 3; ++h) {
            _Float16* qcur = (h == 1) ? Qpong : Qping;
            _Float16* P    = (h == 2) ? P2 : P01;

            gemm_qk_256<<<gS2, dim3(512), 0, stream>>>(
                qcur, (long)LQ * DD, Kh, (long)LKK * DD,
                P, (long)LQ * LKK, partialB, scale);
            if (h == 2)
                scale_attn<<<NB * LQ, blk, 0, stream>>>(P2, partialB, attnF, 8);
            gemm_pc_256x128<<<gP, dim3(512), 0, stream>>>(
                P, (long)LQ * LKK, LKK,
                (const _Float16*)0, 0, 0, LKK * 16,   // ksplit > K: lo only
                Vt, (long)DD * LKK, LKK,
                LKK, 1,
                (float*)0, 0, 0,
                Rh, (long)LQ * DD, DD,
                (const float*)0, partialB, 8);
            _Float16* qn = (h == 0) ? Qpong : (h == 1) ? Qping : (_Float16*)0;
            float* fo = (h == 2) ? outQ : (float*)0;
            gemm_pc_256x128<<<gP, dim3(512), 0, stream>>>(
                qcur, (long)LQ * DD, DD,
                Rh, (long)LQ * DD, DD, DD,            // ksplit = 1024
                Wh, 0, 2 * DD,
                2 * DD, 2,
                fo, (long)LQ * DD, DD,
                qn, (long)LQ * DD, DD,
                bias, (const float*)0, 0);
        }
    } else if (ws_size >= NEED_R3) {
        // -------- proven R3 path --------
        char* ws = (char*)d_ws;
        _Float16* Kh  = (_Float16*)ws;
        _Float16* Vt  = (_Float16*)(ws + 67108864);
        _Float16* Wh  = (_Float16*)(ws + 134217728);
        _Float16* Rh  = (_Float16*)(ws + 138412032);
        _Float16* attn2 = (_Float16*)ws;
        float* Fout = (float*)(ws + 33554432);

        _Float16* Qping = (_Float16*)d_out;
        _Float16* Qpong = Qping + (size_t)NB * LQ * DD;
        float* S = (float*)((char*)d_out + 33554432);
        _Float16* P = (_Float16*)S;
        float* partialB = (float*)((char*)d_out + 73400320);
        float* invB     = (float*)((char*)d_out + 73924608);

        cvt_f32_to_f16<<<4096, blk, 0, stream>>>(Q, Qping, (long)NB * LQ * DD);
        cvt_f32_to_f16<<<16384, blk, 0, stream>>>(Km, Kh, (long)NB * LKK * DD);
        cvt_f32_to_f16<<<1024, blk, 0, stream>>>(W, Wh, (long)DD * 2 * DD);
        transpose_cvt_v<<<dim3(DD / 64, LKK / 64, NB), blk, 0, stream>>>(V, Vt);

        dim3 gS(LKK / 128, LQ / 128, NB);
        dim3 gR(DD / 128, LQ / 128, NB);

        for (int h = 0; h < 3; ++h) {
            _Float16* qcur = (h == 1) ? Qpong : Qping;
            if (h < 2) {
                gemm_f16_nt<<<gS, blk, 0, stream>>>(
                    qcur, (long)LQ * DD, DD, (const _Float16*)0, 0, 0, DD,
                    Kh, (long)LKK * DD, DD, DD,
                    0, scale, (float*)0, 0, 0,
                    P, (long)LQ * LKK, LKK, (const float*)0,
                    partialB, (const float*)0, 16);
                make_inv<<<32, blk, 0, stream>>>(partialB, invB);
                gemm_f16_nt<<<gR, blk, 0, stream>>>(
                    P, (long)LQ * LKK, LKK,
                    (const _Float16*)0, 0, 0, LKK,
                    Vt, (long)DD * LKK, LKK, LKK,
                    1, 1.0f, (float*)0, 0, 0,
                    Rh, (long)LQ * DD, DD, (const float*)0,
                    (float*)0, invB, 0);
            } else {
                gemm_f16_nt<<<gS, blk, 0, stream>>>(
                    qcur, (long)LQ * DD, DD, (const _Float16*)0, 0, 0, DD,
                    Kh, (long)LKK * DD, DD, DD,
                    4, scale, S, (long)LQ * LKK, LKK,
                    (_Float16*)0, 0, 0, (const float*)0,
                    (float*)0, (const float*)0, 0);
                softmax_rows2<<<NB * LQ, blk, 0, stream>>>(S, attn2, 2048L, 1);
                gemm_f16_nt<<<gR, blk, 0, stream>>>(
                    attn2, (long)LQ * LKK, LKK,
                    (const _Float16*)0, 0, 0, LKK,
                    Vt, (long)DD * LKK, LKK, LKK,
                    1, 1.0f, (float*)0, 0, 0,
                    Rh, (long)LQ * DD, DD, (const float*)0,
                    (float*)0, (const float*)0, 0);
            }
            _Float16* qn = (h == 0) ? Qpong : (h == 1) ? Qping : (_Float16*)0;
            float* fo = (h == 2) ? Fout : (float*)0;
            gemm_f16_nt<<<gR, blk, 0, stream>>>(
                qcur, (long)LQ * DD, DD,
                Rh, (long)LQ * DD, DD, DD,
                Wh, 0, 2 * DD, 2 * DD,
                2, 1.0f, fo, (long)LQ * DD, DD,
                qn, (long)LQ * DD, DD, bias,
                (float*)0, (const float*)0, 0);
        }
        hipMemcpyAsync(d_out, Fout, 33554432ULL, hipMemcpyDeviceToDevice, stream);
    } else {
        // -------- round-1 f32 fallback --------
        float* outQ = (float*)d_out;
        float* S    = outQ + (size_t)NB * LQ * DD;
        float* R    = (float*)d_ws;
        float* T    = R + (size_t)NB * LQ * DD;
        dim3 gS(LKK / TN, LQ / TM, NB);
        dim3 gR(DD / TN, LQ / TM, NB);
        for (int h = 0; h < 3; ++h) {
            const float* Qh = (h == 0) ? Q : (h == 1 ? (const float*)T : (const float*)outQ);
            float* cout = (h == 1) ? outQ : T;
            gemm_nt_k<<<gS, blk, 0, stream>>>(Qh, DD, (long)LQ * DD, Km, DD, (long)LKK * DD,
                                              S, LKK, (long)LQ * LKK, DD, scale);
            softmax_rows<<<NB * LQ, blk, 0, stream>>>(S);
            gemm_nn_k<<<gR, blk, 0, stream>>>(S, LKK, (long)LQ * LKK, V, DD, (long)LKK * DD,
                                              R, DD, (long)LQ * DD, LKK);
            gemm_cat_k<<<gR, blk, 0, stream>>>(Qh, R, W, bias, cout);
        }
        hipMemcpyAsync(outQ, T, (size_t)NB * LQ * DD * sizeof(float),
                       hipMemcpyDeviceToDevice, stream);
    }
}